// Round 1
// 717.403 us; speedup vs baseline: 1.1742x; 1.1742x over previous
//
#include <hip/hip_runtime.h>
#include <hip/hip_bf16.h>
#include <cstdint>
#include <cstddef>

#define B_ 2
#define T_ 1024
#define D_ 2048
#define H_ 16
#define DK_ 128
#define DV_ 128
#define ROWS (B_*T_)      // 2048
// Y columns: [q 0:2048 | k 2048:4096 | v 4096:6144 | a 6144:8192 | g 8192:10240 | beta 10240:10256 | pad :10368]
#define NCAT 10368
#define YSTRIDE 10368

typedef __attribute__((ext_vector_type(8))) short bf16x8;
typedef __attribute__((ext_vector_type(4))) float f32x4;
typedef __attribute__((ext_vector_type(2))) float f32x2;

__device__ inline unsigned short f2bf(float f){
    union { float f; unsigned int u; } v; v.f = f;
    unsigned int r = (v.u + 0x7fffu + ((v.u >> 16) & 1u)) >> 16;
    return (unsigned short)r;
}
__device__ inline float sigm(float x){ return 1.0f / (1.0f + __expf(-x)); }

// ---- DPP helpers ----
template<int CTRL>
__device__ __forceinline__ float dpp_add(float x){
    int t = __builtin_amdgcn_update_dpp(0, __builtin_bit_cast(int, x), CTRL, 0xf, 0xf, true);
    return x + __builtin_bit_cast(float, t);
}
// Sum within each 32-lane half. After 5 stages:
//   lane31 = sum(lanes 0..31), lane63 = sum(lanes 32..63). Other lanes partial.
__device__ __forceinline__ float half_sum5(float x){
    x = dpp_add<0x111>(x);   // row_shr:1
    x = dpp_add<0x112>(x);   // row_shr:2
    x = dpp_add<0x114>(x);   // row_shr:4
    x = dpp_add<0x118>(x);   // row_shr:8   lane15/31/47/63 = 16-sums
    x = dpp_add<0x142>(x);   // row_bcast15 lane31 = sum(0..31), lane63 = sum(32..63)
    return x;
}

__device__ __forceinline__ f32x2 pkfma(f32x2 a, f32x2 b, f32x2 c){
    return __builtin_elementwise_fma(a, b, c);
}

__device__ __forceinline__ void gl2lds16(const void* g, void* l){
    __builtin_amdgcn_global_load_lds((const __attribute__((address_space(1))) void*)g,
                                     (__attribute__((address_space(3))) void*)l, 16, 0, 0);
}

// ---------------- fused fp32 -> bf16 casts (one launch) ----------------
struct Cast8 { const float* p[8]; };  // x, Wq, Wk, Wv, Wa, Wg, Wo, Wb
__global__ void cast_all_kernel(Cast8 args, unsigned short* __restrict__ xb,
                                unsigned short* __restrict__ Wcat,
                                unsigned short* __restrict__ Wob){
    int blk = blockIdx.x;
    if (blk >= 28704) {  // zero-pad rows 10256..10367 of Wcat
        int i = (blk - 28704)*1024 + threadIdx.x*4;
        *(ushort4*)(Wcat + (size_t)10256*2048 + i) = (ushort4){0,0,0,0};
        return;
    }
    const float* src; unsigned short* dst; int i;
    if (blk >= 28672) {  // Wb -> Wcat rows 10240..10255
        i = (blk - 28672)*1024 + threadIdx.x*4;
        src = args.p[7]; dst = Wcat + (size_t)10240*2048;
    } else {
        int seg = blk >> 12;
        i = (blk & 4095)*1024 + threadIdx.x*4;
        src = args.p[seg];
        if (seg == 0)      dst = xb;
        else if (seg <= 5) dst = Wcat + (size_t)(seg-1)*4194304;
        else               dst = Wob;
    }
    float4 f = *(const float4*)(src + i);
    ushort4 u; u.x = f2bf(f.x); u.y = f2bf(f.y); u.z = f2bf(f.z); u.w = f2bf(f.w);
    *(ushort4*)(dst + i) = u;
}

// ---------------- bf16 GEMM (m97-style): C[M,N] = A[M,K]*Bm[N,K]^T ----------------
__global__ __launch_bounds__(256) void gemm_bt(
    const unsigned short* __restrict__ A,
    const unsigned short* __restrict__ Bm,
    float* __restrict__ C, int M, int N, int K,
    int act_start, const float* __restrict__ ba, const float* __restrict__ bbeta)
{
    __shared__ __align__(16) unsigned short lA[128*32];
    __shared__ __align__(16) unsigned short lB[128*32];
    const int tid  = threadIdx.x;
    const int wave = tid >> 6, lane = tid & 63;
    const int quad = lane >> 4, l16 = lane & 15;
    const int wm = wave >> 1, wn = wave & 1;
    const int m0 = blockIdx.y * 128, n0 = blockIdx.x * 128;

    const unsigned short* gsrcA[2];
    const unsigned short* gsrcB[2];
    unsigned short* ldst[2];
    #pragma unroll
    for (int i = 0; i < 2; i++) {
        int chunk = wave*128 + i*64 + lane;
        int r = chunk >> 2, p = chunk & 3;
        int gcb = p ^ (r & 3);
        gsrcA[i] = A  + (size_t)(m0 + r)*K + gcb*8;
        gsrcB[i] = Bm + (size_t)(n0 + r)*K + gcb*8;
        ldst[i]  = (unsigned short*)((char*)lA + (size_t)(wave*128 + i*64)*16);
    }
    const size_t lBoff = (size_t)((char*)lB - (char*)lA);

    f32x4 acc[4][4];
    #pragma unroll
    for (int i = 0; i < 4; i++)
        #pragma unroll
        for (int j = 0; j < 4; j++) acc[i][j] = (f32x4){0.f,0.f,0.f,0.f};

    for (int k0 = 0; k0 < K; k0 += 32) {
        __syncthreads();
        #pragma unroll
        for (int i = 0; i < 2; i++) {
            gl2lds16(gsrcA[i] + k0, ldst[i]);
            gl2lds16(gsrcB[i] + k0, (char*)ldst[i] + lBoff);
        }
        __syncthreads();
        bf16x8 af[4], bfr[4];
        #pragma unroll
        for (int i = 0; i < 4; i++) {
            int ra = wm*64 + i*16 + l16;
            int rb = wn*64 + i*16 + l16;
            af[i]  = *(const bf16x8*)(&lA[ra*32 + ((quad ^ (ra & 3))*8)]);
            bfr[i] = *(const bf16x8*)(&lB[rb*32 + ((quad ^ (rb & 3))*8)]);
        }
        #pragma unroll
        for (int i = 0; i < 4; i++)
            #pragma unroll
            for (int j = 0; j < 4; j++)
                acc[i][j] = __builtin_amdgcn_mfma_f32_16x16x32_bf16(af[i], bfr[j], acc[i][j], 0, 0, 0);
    }

    #pragma unroll
    for (int i = 0; i < 4; i++) {
        int m = m0 + wm*64 + i*16 + quad*4;
        #pragma unroll
        for (int j = 0; j < 4; j++) {
            int n = n0 + wn*64 + j*16 + l16;
            #pragma unroll
            for (int r = 0; r < 4; r++) {
                float y = acc[i][j][r];
                if (n >= act_start) {
                    float bsum = 0.0f;
                    if (n < 8192) bsum = ba[n - 6144];
                    else if (n >= 10240 && n < 10256) bsum = bbeta[n - 10240];
                    y = sigm(y + bsum);
                }
                C[(size_t)(m + r)*N + n] = y;
            }
        }
    }
}

// ---------------- causal depthwise conv (K=4) + silu + scale ----------------
__global__ void conv_silu_kernel(const float* __restrict__ Y, int col_off,
                                 const float* __restrict__ cw, const float* __restrict__ cb,
                                 float scale, float* __restrict__ out)
{
    int gid = blockIdx.x * blockDim.x + threadIdx.x;  // 32768 total
    int c = gid & 2047;
    int tmp = gid >> 11;
    int tch = tmp & 7;
    int b = tmp >> 3;
    int t0 = tch * 128;
    const float w0 = cw[c*4+0], w1 = cw[c*4+1], w2 = cw[c*4+2], w3 = cw[c*4+3];
    const float bias = cb[c];
    const float* src = Y + (size_t)b*T_*YSTRIDE + col_off + c;
    float* dst = out + (size_t)b*T_*2048 + c;
    float y0 = (t0 >= 3) ? src[(size_t)(t0-3)*YSTRIDE] : 0.f;
    float y1 = (t0 >= 2) ? src[(size_t)(t0-2)*YSTRIDE] : 0.f;
    float y2 = (t0 >= 1) ? src[(size_t)(t0-1)*YSTRIDE] : 0.f;
    for (int t = t0; t < t0 + 128; t++) {
        float y3 = src[(size_t)t*YSTRIDE];
        float s = fmaf(w0,y0, fmaf(w1,y1, fmaf(w2,y2, fmaf(w3,y3, bias))));
        float r = s * (1.0f/(1.0f + __expf(-s))) * scale;
        dst[(size_t)t*2048] = r;
        y0 = y1; y1 = y2; y2 = y3;
    }
}

// ---------------- gated delta recurrence: 2 v-rows per wave (half-wave each) ----------------
// Lanes 0-31 own row rowA, lanes 32-63 own row rowA+64, 4 k-dims per lane (float4).
// Per step: sk reduce = 5 DPP stages (both halves simultaneously; sums land in
// lanes 31/63), c computed locally there, broadcast to each half via one
// ds_swizzle (lane -> (lane&~31)|31).  o-sum lands directly in the storing
// lanes 31/63 -- no broadcast needed.
// blk = rowgrp*32 + bh -> XCD = blk%8 = bh%8: all blocks of a (b,h) share an
// XCD for k/q L2 locality (unchanged from the 1-row/wave version).
__global__ __launch_bounds__(256) void recurrence_kernel(
    const float* __restrict__ q, const float* __restrict__ k, const float* __restrict__ v,
    const float* __restrict__ a, const float* __restrict__ beta, float* __restrict__ o)
{
    const int blk = blockIdx.x;
    const int bh = blk & 31;
    const int rowgrp = blk >> 5;          // 0..15
    const int h = bh & 15, b = bh >> 4;
    const int lane = threadIdx.x & 63;
    const int wave = threadIdx.x >> 6;
    const int rowA = rowgrp*4 + wave;     // 0..63
    const int vrow = (lane < 32) ? rowA : rowA + 64;
    const size_t rbase = (size_t)b * T_;
    // both halves load the same k/q row (dims 4*(lane&31) .. +3); step stride 512 float4
    const float4* kp = (const float4*)(k + rbase*2048 + (size_t)h*128) + (lane & 31);
    const float4* qp = (const float4*)(q + rbase*2048 + (size_t)h*128) + (lane & 31);
    const float*  vp = v + rbase*2048 + h*128 + vrow;
    const float*  ap = a + rbase*YSTRIDE + h*128 + vrow;
    const float*  bp = beta + rbase*YSTRIDE + h;
    float*        op = o + rbase*2048 + h*128 + vrow;

    f32x2 s01 = {0.f, 0.f}, s23 = {0.f, 0.f};
    float4 kc[4], qc[4], kn[4], qn[4];
    float  vc[4], ac[4], bc[4], vn[4], an[4], bn[4];

    #pragma unroll
    for (int j = 0; j < 4; j++) {
        kc[j] = kp[j*512]; qc[j] = qp[j*512];
        vc[j] = vp[(size_t)j*2048]; ac[j] = ap[(size_t)j*YSTRIDE]; bc[j] = bp[(size_t)j*YSTRIDE];
    }

#define RSTEP(kv, qv, vt, at, bt, oidx) { \
    f32x2 k01 = {(kv).x, (kv).y}, k23 = {(kv).z, (kv).w}; \
    f32x2 q01 = {(qv).x, (qv).y}, q23 = {(qv).z, (qv).w}; \
    f32x2 d2 = pkfma(s23, k23, s01*k01); \
    float sk = d2.x + d2.y; \
    sk = half_sum5(sk); \
    float cl = (bt) * (sk - (vt)); \
    cl = __builtin_bit_cast(float, __builtin_amdgcn_ds_swizzle(__builtin_bit_cast(int, cl), 0x03E0)); \
    f32x2 c2 = {cl, cl}; \
    f32x2 a2 = {(at), (at)}; \
    s01 = pkfma(a2, s01, -(c2*k01)); \
    s23 = pkfma(a2, s23, -(c2*k23)); \
    f32x2 o2 = pkfma(s23, q23, s01*q01); \
    float ov_ = o2.x + o2.y; \
    ov_ = half_sum5(ov_); \
    if ((lane & 31) == 31) op[(size_t)(oidx)*2048] = ov_; \
}

    #pragma unroll 1
    for (int t0 = 0; t0 < T_; t0 += 8) {
        // prefetch t0+4..7 (group n)
        #pragma unroll
        for (int j = 0; j < 4; j++) {
            int t = t0 + 4 + j;
            kn[j] = kp[t*512]; qn[j] = qp[t*512];
            vn[j] = vp[(size_t)t*2048]; an[j] = ap[(size_t)t*YSTRIDE]; bn[j] = bp[(size_t)t*YSTRIDE];
        }
        // compute group c at t0..t0+3
        #pragma unroll
        for (int j = 0; j < 4; j++) RSTEP(kc[j], qc[j], vc[j], ac[j], bc[j], t0+j);
        // prefetch t0+8..11 into group c (last iter overruns into adjacent ws arrays; values unused)
        #pragma unroll
        for (int j = 0; j < 4; j++) {
            int t = t0 + 8 + j;
            kc[j] = kp[t*512]; qc[j] = qp[t*512];
            vc[j] = vp[(size_t)t*2048]; ac[j] = ap[(size_t)t*YSTRIDE]; bc[j] = bp[(size_t)t*YSTRIDE];
        }
        // compute group n at t0+4..t0+7
        #pragma unroll
        for (int j = 0; j < 4; j++) RSTEP(kn[j], qn[j], vn[j], an[j], bn[j], t0+4+j);
    }
#undef RSTEP
}

// ---------------- LayerNorm over DV, * gate, -> bf16 ----------------
__global__ __launch_bounds__(256) void ln_gate_kernel(
    const float* __restrict__ o, const float* __restrict__ g, int g_stride,
    const float* __restrict__ ln_g, const float* __restrict__ ln_b,
    unsigned short* __restrict__ og)
{
    int wave = threadIdx.x >> 6, lane = threadIdx.x & 63;
    int gidx = blockIdx.x*4 + wave;     // 0..32767
    int row = gidx >> 4, h = gidx & 15;
    const float* ob = o + (size_t)row*2048 + h*128;
    int d0 = lane*2;
    float2 xv = *(const float2*)(ob + d0);
    float s = xv.x + xv.y, ss = xv.x*xv.x + xv.y*xv.y;
    for (int m = 1; m < 64; m <<= 1) { s += __shfl_xor(s, m); ss += __shfl_xor(ss, m); }
    float mu  = s * (1.f/128.f);
    float var = ss * (1.f/128.f) - mu*mu;
    float inv = rsqrtf(var + 1e-5f);
    const float* gb = g + (size_t)row*g_stride + h*128;
    float r0 = ((xv.x - mu)*inv*ln_g[d0]   + ln_b[d0])   * gb[d0];
    float r1 = ((xv.y - mu)*inv*ln_g[d0+1] + ln_b[d0+1]) * gb[d0+1];
    ushort2 u; u.x = f2bf(r0); u.y = f2bf(r1);
    *(ushort2*)(og + (size_t)row*2048 + h*128 + d0) = u;
}

extern "C" void kernel_launch(void* const* d_in, const int* in_sizes, int n_in,
                              void* d_out, int out_size, void* d_ws, size_t ws_size,
                              hipStream_t stream)
{
    const float* x   = (const float*)d_in[0];
    const float* Wq  = (const float*)d_in[1];
    const float* Wk  = (const float*)d_in[2];
    const float* Wv  = (const float*)d_in[3];
    const float* Wa  = (const float*)d_in[4];
    const float* ba  = (const float*)d_in[5];
    const float* Wb  = (const float*)d_in[6];
    const float* bb  = (const float*)d_in[7];
    const float* cqw = (const float*)d_in[8];
    const float* cqb = (const float*)d_in[9];
    const float* ckw = (const float*)d_in[10];
    const float* ckb = (const float*)d_in[11];
    const float* cvw = (const float*)d_in[12];
    const float* cvb = (const float*)d_in[13];
    const float* Wg  = (const float*)d_in[14];
    const float* lng = (const float*)d_in[15];
    const float* lnb = (const float*)d_in[16];
    const float* Wo  = (const float*)d_in[17];
    float* out = (float*)d_out;

    char* ws = (char*)d_ws;
    size_t off = 0;
    auto alloc = [&](size_t bytes){ void* p = ws + off; off += (bytes + 255) & ~(size_t)255; return p; };
    unsigned short* xb   = (unsigned short*)alloc((size_t)ROWS*D_*2);   // reused as og
    unsigned short* Wcat = (unsigned short*)alloc((size_t)NCAT*D_*2);
    unsigned short* Wob  = (unsigned short*)alloc((size_t)D_*D_*2);
    float* Y  = (float*)alloc((size_t)ROWS*YSTRIDE*4);
    float* qs = (float*)alloc((size_t)ROWS*2048*4);
    float* ks = (float*)alloc((size_t)ROWS*2048*4);
    float* vs = (float*)alloc((size_t)ROWS*2048*4);
    float* ov = (float*)alloc((size_t)ROWS*2048*4);
    unsigned short* og = xb;
    (void)ws_size;

    Cast8 cargs;
    cargs.p[0]=x; cargs.p[1]=Wq; cargs.p[2]=Wk; cargs.p[3]=Wv; cargs.p[4]=Wa;
    cargs.p[5]=Wg; cargs.p[6]=Wo; cargs.p[7]=Wb;
    cast_all_kernel<<<28928, 256, 0, stream>>>(cargs, xb, Wcat, Wob);

    // fused projections + beta: [2048,10368] = xb @ Wcat^T
    gemm_bt<<<dim3(81,16), 256, 0, stream>>>(xb, Wcat, Y, ROWS, NCAT, D_, 6144, ba, bb);

    const float kscale = 0.08838834764831845f;  // DK^-0.5
    conv_silu_kernel<<<128, 256, 0, stream>>>(Y, 0,    cqw, cqb, 1.0f,   qs);
    conv_silu_kernel<<<128, 256, 0, stream>>>(Y, 2048, ckw, ckb, kscale, ks);
    conv_silu_kernel<<<128, 256, 0, stream>>>(Y, 4096, cvw, cvb, 1.0f,   vs);

    // 512 blocks x 4 waves; each wave: 2 v-rows (halves of the wave)
    recurrence_kernel<<<512, 256, 0, stream>>>(qs, ks, vs, Y + 6144, Y + 10240, ov);

    ln_gate_kernel<<<8192, 256, 0, stream>>>(ov, Y + 8192, YSTRIDE, lng, lnb, og);

    gemm_bt<<<dim3(16,16), 256, 0, stream>>>(og, Wob, out, ROWS, D_, D_, 1<<30, nullptr, nullptr);
}

// Round 5
// 677.916 us; speedup vs baseline: 1.2426x; 1.0582x over previous
//
#include <hip/hip_runtime.h>
#include <hip/hip_bf16.h>
#include <cstdint>
#include <cstddef>

#define B_ 2
#define T_ 1024
#define D_ 2048
#define H_ 16
#define DK_ 128
#define DV_ 128
#define ROWS (B_*T_)      // 2048
// Y columns: [q 0:2048 | k 2048:4096 | v 4096:6144 | a 6144:8192 | g 8192:10240 | beta 10240:10256 | pad :10368]
#define NCAT 10368
#define YSTRIDE 10368

typedef __attribute__((ext_vector_type(8))) short bf16x8;
typedef __attribute__((ext_vector_type(4))) float f32x4;
typedef __attribute__((ext_vector_type(2))) float f32x2;

__device__ inline unsigned short f2bf(float f){
    union { float f; unsigned int u; } v; v.f = f;
    unsigned int r = (v.u + 0x7fffu + ((v.u >> 16) & 1u)) >> 16;
    return (unsigned short)r;
}
__device__ inline float sigm(float x){ return 1.0f / (1.0f + __expf(-x)); }

// ---- DPP helpers (PROVEN in rounds 0/1) ----
template<int CTRL>
__device__ __forceinline__ float dpp_add(float x){
    int t = __builtin_amdgcn_update_dpp(0, __builtin_bit_cast(int, x), CTRL, 0xf, 0xf, true);
    return x + __builtin_bit_cast(float, t);
}
// Sum within each 32-lane half. After 5 stages:
//   lane31 = sum(lanes 0..31), lane63 = sum(lanes 32..63). Other lanes partial.
__device__ __forceinline__ float half_sum5(float x){
    x = dpp_add<0x111>(x);   // row_shr:1
    x = dpp_add<0x112>(x);   // row_shr:2
    x = dpp_add<0x114>(x);   // row_shr:4
    x = dpp_add<0x118>(x);   // row_shr:8   lane15/31/47/63 = 16-sums
    x = dpp_add<0x142>(x);   // row_bcast15 lane31 = sum(0..31), lane63 = sum(32..63)
    return x;
}

__device__ __forceinline__ f32x2 pkfma(f32x2 a, f32x2 b, f32x2 c){
    return __builtin_elementwise_fma(a, b, c);
}

__device__ __forceinline__ void gl2lds16(const void* g, void* l){
    __builtin_amdgcn_global_load_lds((const __attribute__((address_space(1))) void*)g,
                                     (__attribute__((address_space(3))) void*)l, 16, 0, 0);
}

// ---------------- fused fp32 -> bf16 casts (one launch) ----------------
struct Cast8 { const float* p[8]; };  // x, Wq, Wk, Wv, Wa, Wg, Wo, Wb
__global__ void cast_all_kernel(Cast8 args, unsigned short* __restrict__ xb,
                                unsigned short* __restrict__ Wcat,
                                unsigned short* __restrict__ Wob){
    int blk = blockIdx.x;
    if (blk >= 28704) {  // zero-pad rows 10256..10367 of Wcat
        int i = (blk - 28704)*1024 + threadIdx.x*4;
        *(ushort4*)(Wcat + (size_t)10256*2048 + i) = (ushort4){0,0,0,0};
        return;
    }
    const float* src; unsigned short* dst; int i;
    if (blk >= 28672) {  // Wb -> Wcat rows 10240..10255
        i = (blk - 28672)*1024 + threadIdx.x*4;
        src = args.p[7]; dst = Wcat + (size_t)10240*2048;
    } else {
        int seg = blk >> 12;
        i = (blk & 4095)*1024 + threadIdx.x*4;
        src = args.p[seg];
        if (seg == 0)      dst = xb;
        else if (seg <= 5) dst = Wcat + (size_t)(seg-1)*4194304;
        else               dst = Wob;
    }
    float4 f = *(const float4*)(src + i);
    ushort4 u; u.x = f2bf(f.x); u.y = f2bf(f.y); u.z = f2bf(f.z); u.w = f2bf(f.w);
    *(ushort4*)(dst + i) = u;
}

// ---------------- bf16 GEMM (m97-style): C[M,N] = A[M,K]*Bm[N,K]^T ----------------
__global__ __launch_bounds__(256) void gemm_bt(
    const unsigned short* __restrict__ A,
    const unsigned short* __restrict__ Bm,
    float* __restrict__ C, int M, int N, int K,
    int act_start, const float* __restrict__ ba, const float* __restrict__ bbeta)
{
    __shared__ __align__(16) unsigned short lA[128*32];
    __shared__ __align__(16) unsigned short lB[128*32];
    const int tid  = threadIdx.x;
    const int wave = tid >> 6, lane = tid & 63;
    const int quad = lane >> 4, l16 = lane & 15;
    const int wm = wave >> 1, wn = wave & 1;
    const int m0 = blockIdx.y * 128, n0 = blockIdx.x * 128;

    const unsigned short* gsrcA[2];
    const unsigned short* gsrcB[2];
    unsigned short* ldst[2];
    #pragma unroll
    for (int i = 0; i < 2; i++) {
        int chunk = wave*128 + i*64 + lane;
        int r = chunk >> 2, p = chunk & 3;
        int gcb = p ^ (r & 3);
        gsrcA[i] = A  + (size_t)(m0 + r)*K + gcb*8;
        gsrcB[i] = Bm + (size_t)(n0 + r)*K + gcb*8;
        ldst[i]  = (unsigned short*)((char*)lA + (size_t)(wave*128 + i*64)*16);
    }
    const size_t lBoff = (size_t)((char*)lB - (char*)lA);

    f32x4 acc[4][4];
    #pragma unroll
    for (int i = 0; i < 4; i++)
        #pragma unroll
        for (int j = 0; j < 4; j++) acc[i][j] = (f32x4){0.f,0.f,0.f,0.f};

    for (int k0 = 0; k0 < K; k0 += 32) {
        __syncthreads();
        #pragma unroll
        for (int i = 0; i < 2; i++) {
            gl2lds16(gsrcA[i] + k0, ldst[i]);
            gl2lds16(gsrcB[i] + k0, (char*)ldst[i] + lBoff);
        }
        __syncthreads();
        bf16x8 af[4], bfr[4];
        #pragma unroll
        for (int i = 0; i < 4; i++) {
            int ra = wm*64 + i*16 + l16;
            int rb = wn*64 + i*16 + l16;
            af[i]  = *(const bf16x8*)(&lA[ra*32 + ((quad ^ (ra & 3))*8)]);
            bfr[i] = *(const bf16x8*)(&lB[rb*32 + ((quad ^ (rb & 3))*8)]);
        }
        #pragma unroll
        for (int i = 0; i < 4; i++)
            #pragma unroll
            for (int j = 0; j < 4; j++)
                acc[i][j] = __builtin_amdgcn_mfma_f32_16x16x32_bf16(af[i], bfr[j], acc[i][j], 0, 0, 0);
    }

    #pragma unroll
    for (int i = 0; i < 4; i++) {
        int m = m0 + wm*64 + i*16 + quad*4;
        #pragma unroll
        for (int j = 0; j < 4; j++) {
            int n = n0 + wn*64 + j*16 + l16;
            #pragma unroll
            for (int r = 0; r < 4; r++) {
                float y = acc[i][j][r];
                if (n >= act_start) {
                    float bsum = 0.0f;
                    if (n < 8192) bsum = ba[n - 6144];
                    else if (n >= 10240 && n < 10256) bsum = bbeta[n - 10240];
                    y = sigm(y + bsum);
                }
                C[(size_t)(m + r)*N + n] = y;
            }
        }
    }
}

// ---------------- causal depthwise conv (K=4) + silu + scale; writes PACKED [bh][t][dim] ----------------
__global__ void conv_silu_kernel(const float* __restrict__ Y, int col_off,
                                 const float* __restrict__ cw, const float* __restrict__ cb,
                                 float scale, float* __restrict__ out)
{
    int gid = blockIdx.x * blockDim.x + threadIdx.x;  // 32768 total
    int c = gid & 2047;
    int tmp = gid >> 11;
    int tch = tmp & 7;
    int b = tmp >> 3;
    int t0 = tch * 128;
    const float w0 = cw[c*4+0], w1 = cw[c*4+1], w2 = cw[c*4+2], w3 = cw[c*4+3];
    const float bias = cb[c];
    const float* src = Y + (size_t)b*T_*YSTRIDE + col_off + c;
    // packed: out[(b*16+h)*1024*128 + t*128 + dim]
    float* dst = out + (size_t)(b*16 + (c >> 7))*131072 + (c & 127);
    float y0 = (t0 >= 3) ? src[(size_t)(t0-3)*YSTRIDE] : 0.f;
    float y1 = (t0 >= 2) ? src[(size_t)(t0-2)*YSTRIDE] : 0.f;
    float y2 = (t0 >= 1) ? src[(size_t)(t0-1)*YSTRIDE] : 0.f;
    for (int t = t0; t < t0 + 128; t++) {
        float y3 = src[(size_t)t*YSTRIDE];
        float s = fmaf(w0,y0, fmaf(w1,y1, fmaf(w2,y2, fmaf(w3,y3, bias))));
        float r = s * (1.0f/(1.0f + __expf(-s))) * scale;
        dst[(size_t)t*128] = r;
        y0 = y1; y1 = y2; y2 = y3;
    }
}

// ---------------- pack a (sigmoided) and beta out of Y into [bh][t][.] ----------------
__global__ void pack_ab_kernel(const float* __restrict__ Y,
                               float* __restrict__ apack, float* __restrict__ bpack)
{
    int blk = blockIdx.x;
    if (blk < 4096) {
        int gid = blk*256 + threadIdx.x;        // 0..1048575
        int r  = gid >> 9;                      // row 0..2047
        int c4 = gid & 511;                     // float4 col within a-block
        int h = c4 >> 5, dim4 = c4 & 31;
        int b = r >> 10, t = r & 1023;
        float4 f = *(const float4*)(Y + (size_t)r*YSTRIDE + 6144 + c4*4);
        *(float4*)(apack + (size_t)(b*16 + h)*131072 + t*128 + dim4*4) = f;
    } else {
        int gid = (blk - 4096)*256 + threadIdx.x;  // 0..32767
        int r = gid >> 4, h = gid & 15;
        int b = r >> 10, t = r & 1023;
        bpack[(size_t)(b*16 + h)*1024 + t] = Y[(size_t)r*YSTRIDE + 10240 + h];
    }
}

// ---------------- gated delta recurrence: 2 v-rows per wave (PROVEN round-1 internals, packed addrs) ----
// Lanes 0-31 own row rowA, lanes 32-63 own row rowA+64; 4 k-dims per lane
// (float4, d4 = lane&31 -> dims 4*d4..4*d4+3; both halves read the same k/q).
// half_sum5 (row_shr tree + row_bcast15) leaves row-A's full 128-dot in lane31
// and row-B's in lane63; c computed there, broadcast to each half via one
// ds_swizzle (lane -> (lane&~31)|31).  o-sum lands in lanes 31/63 -> store.
// All streams packed [bh][t][.]: 512B/step sequential, immediate-offset
// addressing. blk = rowgrp*32 + bh -> XCD = bh%8 shared per (b,h).
__global__ __launch_bounds__(256) void recurrence_kernel(
    const float* __restrict__ q, const float* __restrict__ k, const float* __restrict__ v,
    const float* __restrict__ a, const float* __restrict__ beta, float* __restrict__ o)
{
    const int blk = blockIdx.x;
    const int bh = blk & 31;              // == b*16 + h
    const int rowgrp = blk >> 5;          // 0..15
    const int lane = threadIdx.x & 63;
    const int wave = threadIdx.x >> 6;
    const int rowA = rowgrp*4 + wave;     // 0..63
    const int vrow = (lane < 32) ? rowA : rowA + 64;
    const size_t cb = (size_t)bh * 131072;
    const float4* kp = (const float4*)(k + cb) + (lane & 31);  // step stride 32 float4
    const float4* qp = (const float4*)(q + cb) + (lane & 31);
    const float*  vp = v + cb + vrow;
    const float*  ap = a + cb + vrow;
    const float*  bp = beta + (size_t)bh * 1024;
    float*        op = o + cb + vrow;

    f32x2 s01 = {0.f, 0.f}, s23 = {0.f, 0.f};
    float4 kc[4], qc[4], kn[4], qn[4];
    float  vc[4], ac[4], bc[4], vn[4], an[4], bn[4];

    #pragma unroll
    for (int j = 0; j < 4; j++) {
        kc[j] = kp[j*32]; qc[j] = qp[j*32];
        vc[j] = vp[j*128]; ac[j] = ap[j*128]; bc[j] = bp[j];
    }

#define RSTEP(kv, qv, vt, at, bt, oidx) { \
    f32x2 k01 = {(kv).x, (kv).y}, k23 = {(kv).z, (kv).w}; \
    f32x2 q01 = {(qv).x, (qv).y}, q23 = {(qv).z, (qv).w}; \
    f32x2 d2 = pkfma(s23, k23, s01*k01); \
    float sk = d2.x + d2.y; \
    sk = half_sum5(sk); \
    float cl = (bt) * (sk - (vt)); \
    cl = __builtin_bit_cast(float, __builtin_amdgcn_ds_swizzle(__builtin_bit_cast(int, cl), 0x03E0)); \
    f32x2 c2 = {cl, cl}; \
    f32x2 a2 = {(at), (at)}; \
    s01 = pkfma(a2, s01, -(c2*k01)); \
    s23 = pkfma(a2, s23, -(c2*k23)); \
    f32x2 o2 = pkfma(s23, q23, s01*q01); \
    float ov_ = o2.x + o2.y; \
    ov_ = half_sum5(ov_); \
    if ((lane & 31) == 31) op[(size_t)(oidx)*128] = ov_; \
}

    #pragma unroll 1
    for (int t0 = 0; t0 < T_; t0 += 8) {
        // prefetch t0+4..7 (group n)
        #pragma unroll
        for (int j = 0; j < 4; j++) {
            int t = t0 + 4 + j;
            kn[j] = kp[t*32]; qn[j] = qp[t*32];
            vn[j] = vp[(size_t)t*128]; an[j] = ap[(size_t)t*128]; bn[j] = bp[t];
        }
        // compute group c at t0..t0+3
        #pragma unroll
        for (int j = 0; j < 4; j++) RSTEP(kc[j], qc[j], vc[j], ac[j], bc[j], t0+j);
        // prefetch t0+8..11 into group c (last iter overruns into adjacent ws arrays; values unused)
        #pragma unroll
        for (int j = 0; j < 4; j++) {
            int t = t0 + 8 + j;
            kc[j] = kp[t*32]; qc[j] = qp[t*32];
            vc[j] = vp[(size_t)t*128]; ac[j] = ap[(size_t)t*128]; bc[j] = bp[t];
        }
        // compute group n at t0+4..t0+7
        #pragma unroll
        for (int j = 0; j < 4; j++) RSTEP(kn[j], qn[j], vn[j], an[j], bn[j], t0+4+j);
    }
#undef RSTEP
}

// ---------------- LayerNorm over DV, * gate, -> bf16 (reads packed ov) ----------------
__global__ __launch_bounds__(256) void ln_gate_kernel(
    const float* __restrict__ o, const float* __restrict__ g, int g_stride,
    const float* __restrict__ ln_g, const float* __restrict__ ln_b,
    unsigned short* __restrict__ og)
{
    int wave = threadIdx.x >> 6, lane = threadIdx.x & 63;
    int gidx = blockIdx.x*4 + wave;     // 0..32767
    int row = gidx >> 4, h = gidx & 15;
    int b = row >> 10, t = row & 1023;
    const float* ob = o + (size_t)(b*16 + h)*131072 + (size_t)t*128;
    int d0 = lane*2;
    float2 xv = *(const float2*)(ob + d0);
    float s = xv.x + xv.y, ss = xv.x*xv.x + xv.y*xv.y;
    for (int m = 1; m < 64; m <<= 1) { s += __shfl_xor(s, m); ss += __shfl_xor(ss, m); }
    float mu  = s * (1.f/128.f);
    float var = ss * (1.f/128.f) - mu*mu;
    float inv = rsqrtf(var + 1e-5f);
    const float* gb = g + (size_t)row*g_stride + h*128;
    float r0 = ((xv.x - mu)*inv*ln_g[d0]   + ln_b[d0])   * gb[d0];
    float r1 = ((xv.y - mu)*inv*ln_g[d0+1] + ln_b[d0+1]) * gb[d0+1];
    ushort2 u; u.x = f2bf(r0); u.y = f2bf(r1);
    *(ushort2*)(og + (size_t)row*2048 + h*128 + d0) = u;
}

extern "C" void kernel_launch(void* const* d_in, const int* in_sizes, int n_in,
                              void* d_out, int out_size, void* d_ws, size_t ws_size,
                              hipStream_t stream)
{
    const float* x   = (const float*)d_in[0];
    const float* Wq  = (const float*)d_in[1];
    const float* Wk  = (const float*)d_in[2];
    const float* Wv  = (const float*)d_in[3];
    const float* Wa  = (const float*)d_in[4];
    const float* ba  = (const float*)d_in[5];
    const float* Wb  = (const float*)d_in[6];
    const float* bb  = (const float*)d_in[7];
    const float* cqw = (const float*)d_in[8];
    const float* cqb = (const float*)d_in[9];
    const float* ckw = (const float*)d_in[10];
    const float* ckb = (const float*)d_in[11];
    const float* cvw = (const float*)d_in[12];
    const float* cvb = (const float*)d_in[13];
    const float* Wg  = (const float*)d_in[14];
    const float* lng = (const float*)d_in[15];
    const float* lnb = (const float*)d_in[16];
    const float* Wo  = (const float*)d_in[17];
    float* out = (float*)d_out;

    char* ws = (char*)d_ws;
    size_t off = 0;
    auto alloc = [&](size_t bytes){ void* p = ws + off; off += (bytes + 255) & ~(size_t)255; return p; };
    unsigned short* xb   = (unsigned short*)alloc((size_t)ROWS*D_*2);   // reused as og
    unsigned short* Wcat = (unsigned short*)alloc((size_t)NCAT*D_*2);   // reused as apack/bpack after gemm1
    unsigned short* Wob  = (unsigned short*)alloc((size_t)D_*D_*2);
    float* Y  = (float*)alloc((size_t)ROWS*YSTRIDE*4);
    float* qs = (float*)alloc((size_t)ROWS*2048*4);   // packed [bh][t][128]
    float* ks = (float*)alloc((size_t)ROWS*2048*4);   // packed
    float* vs = (float*)alloc((size_t)ROWS*2048*4);   // packed
    float* ov = (float*)alloc((size_t)ROWS*2048*4);   // packed
    unsigned short* og = xb;
    float* apack = (float*)Wcat;                       // 16MB, alias (Wcat dead after gemm1)
    float* bpack = apack + (size_t)32*1024*128;        // 128KB, still within Wcat
    (void)ws_size;

    Cast8 cargs;
    cargs.p[0]=x; cargs.p[1]=Wq; cargs.p[2]=Wk; cargs.p[3]=Wv; cargs.p[4]=Wa;
    cargs.p[5]=Wg; cargs.p[6]=Wo; cargs.p[7]=Wb;
    cast_all_kernel<<<28928, 256, 0, stream>>>(cargs, xb, Wcat, Wob);

    // fused projections + beta: [2048,10368] = xb @ Wcat^T
    gemm_bt<<<dim3(81,16), 256, 0, stream>>>(xb, Wcat, Y, ROWS, NCAT, D_, 6144, ba, bb);

    // pack a/beta into [bh][t][.] (overwrites Wcat region -- gemm1 already done)
    pack_ab_kernel<<<4224, 256, 0, stream>>>(Y, apack, bpack);

    const float kscale = 0.08838834764831845f;  // DK^-0.5
    conv_silu_kernel<<<128, 256, 0, stream>>>(Y, 0,    cqw, cqb, 1.0f,   qs);
    conv_silu_kernel<<<128, 256, 0, stream>>>(Y, 2048, ckw, ckb, kscale, ks);
    conv_silu_kernel<<<128, 256, 0, stream>>>(Y, 4096, cvw, cvb, 1.0f,   vs);

    // 512 blocks x 4 waves; each wave: 2 v-rows (lane halves)
    recurrence_kernel<<<512, 256, 0, stream>>>(qs, ks, vs, apack, bpack, ov);

    ln_gate_kernel<<<8192, 256, 0, stream>>>(ov, Y + 8192, YSTRIDE, lng, lnb, og);

    gemm_bt<<<dim3(16,16), 256, 0, stream>>>(og, Wob, out, ROWS, D_, D_, 1<<30, nullptr, nullptr);
}

// Round 6
// 675.576 us; speedup vs baseline: 1.2469x; 1.0035x over previous
//
#include <hip/hip_runtime.h>
#include <hip/hip_bf16.h>
#include <cstdint>
#include <cstddef>

#define B_ 2
#define T_ 1024
#define D_ 2048
#define H_ 16
#define DK_ 128
#define DV_ 128
#define ROWS (B_*T_)      // 2048
// Y columns: [q 0:2048 | k 2048:4096 | v 4096:6144 | a 6144:8192 | g 8192:10240 | beta 10240:10256 | pad :10368]
#define NCAT 10368
#define YSTRIDE 10368

typedef __attribute__((ext_vector_type(8))) short bf16x8;
typedef __attribute__((ext_vector_type(4))) float f32x4;
typedef __attribute__((ext_vector_type(2))) float f32x2;

__device__ inline unsigned short f2bf(float f){
    union { float f; unsigned int u; } v; v.f = f;
    unsigned int r = (v.u + 0x7fffu + ((v.u >> 16) & 1u)) >> 16;
    return (unsigned short)r;
}
__device__ inline float sigm(float x){ return 1.0f / (1.0f + __expf(-x)); }

// ---- DPP helpers (PROVEN rounds 0/1/5) ----
template<int CTRL>
__device__ __forceinline__ float dpp_add(float x){
    int t = __builtin_amdgcn_update_dpp(0, __builtin_bit_cast(int, x), CTRL, 0xf, 0xf, true);
    return x + __builtin_bit_cast(float, t);
}
// Sum within each 32-lane half. After 5 stages:
//   lane31 = sum(lanes 0..31), lane63 = sum(lanes 32..63). Other lanes partial.
__device__ __forceinline__ float half_sum5(float x){
    x = dpp_add<0x111>(x);   // row_shr:1
    x = dpp_add<0x112>(x);   // row_shr:2
    x = dpp_add<0x114>(x);   // row_shr:4
    x = dpp_add<0x118>(x);   // row_shr:8   lane15/31/47/63 = 16-sums
    x = dpp_add<0x142>(x);   // row_bcast15 lane31 = sum(0..31), lane63 = sum(32..63)
    return x;
}

__device__ __forceinline__ f32x2 pkfma(f32x2 a, f32x2 b, f32x2 c){
    return __builtin_elementwise_fma(a, b, c);
}

__device__ __forceinline__ void gl2lds16(const void* g, void* l){
    __builtin_amdgcn_global_load_lds((const __attribute__((address_space(1))) void*)g,
                                     (__attribute__((address_space(3))) void*)l, 16, 0, 0);
}

// ---------------- fused fp32 -> bf16 casts (one launch) ----------------
struct Cast8 { const float* p[8]; };  // x, Wq, Wk, Wv, Wa, Wg, Wo, Wb
__global__ void cast_all_kernel(Cast8 args, unsigned short* __restrict__ xb,
                                unsigned short* __restrict__ Wcat,
                                unsigned short* __restrict__ Wob){
    int blk = blockIdx.x;
    if (blk >= 28704) {  // zero-pad rows 10256..10367 of Wcat
        int i = (blk - 28704)*1024 + threadIdx.x*4;
        *(ushort4*)(Wcat + (size_t)10256*2048 + i) = (ushort4){0,0,0,0};
        return;
    }
    const float* src; unsigned short* dst; int i;
    if (blk >= 28672) {  // Wb -> Wcat rows 10240..10255
        i = (blk - 28672)*1024 + threadIdx.x*4;
        src = args.p[7]; dst = Wcat + (size_t)10240*2048;
    } else {
        int seg = blk >> 12;
        i = (blk & 4095)*1024 + threadIdx.x*4;
        src = args.p[seg];
        if (seg == 0)      dst = xb;
        else if (seg <= 5) dst = Wcat + (size_t)(seg-1)*4194304;
        else               dst = Wob;
    }
    float4 f = *(const float4*)(src + i);
    ushort4 u; u.x = f2bf(f.x); u.y = f2bf(f.y); u.z = f2bf(f.z); u.w = f2bf(f.w);
    *(ushort4*)(dst + i) = u;
}

// ---------------- bf16 GEMM (m97-style): C[M,N] = A[M,K]*Bm[N,K]^T ----------------
__global__ __launch_bounds__(256) void gemm_bt(
    const unsigned short* __restrict__ A,
    const unsigned short* __restrict__ Bm,
    float* __restrict__ C, int M, int N, int K,
    int act_start, const float* __restrict__ ba, const float* __restrict__ bbeta)
{
    __shared__ __align__(16) unsigned short lA[128*32];
    __shared__ __align__(16) unsigned short lB[128*32];
    const int tid  = threadIdx.x;
    const int wave = tid >> 6, lane = tid & 63;
    const int quad = lane >> 4, l16 = lane & 15;
    const int wm = wave >> 1, wn = wave & 1;
    const int m0 = blockIdx.y * 128, n0 = blockIdx.x * 128;

    const unsigned short* gsrcA[2];
    const unsigned short* gsrcB[2];
    unsigned short* ldst[2];
    #pragma unroll
    for (int i = 0; i < 2; i++) {
        int chunk = wave*128 + i*64 + lane;
        int r = chunk >> 2, p = chunk & 3;
        int gcb = p ^ (r & 3);
        gsrcA[i] = A  + (size_t)(m0 + r)*K + gcb*8;
        gsrcB[i] = Bm + (size_t)(n0 + r)*K + gcb*8;
        ldst[i]  = (unsigned short*)((char*)lA + (size_t)(wave*128 + i*64)*16);
    }
    const size_t lBoff = (size_t)((char*)lB - (char*)lA);

    f32x4 acc[4][4];
    #pragma unroll
    for (int i = 0; i < 4; i++)
        #pragma unroll
        for (int j = 0; j < 4; j++) acc[i][j] = (f32x4){0.f,0.f,0.f,0.f};

    for (int k0 = 0; k0 < K; k0 += 32) {
        __syncthreads();
        #pragma unroll
        for (int i = 0; i < 2; i++) {
            gl2lds16(gsrcA[i] + k0, ldst[i]);
            gl2lds16(gsrcB[i] + k0, (char*)ldst[i] + lBoff);
        }
        __syncthreads();
        bf16x8 af[4], bfr[4];
        #pragma unroll
        for (int i = 0; i < 4; i++) {
            int ra = wm*64 + i*16 + l16;
            int rb = wn*64 + i*16 + l16;
            af[i]  = *(const bf16x8*)(&lA[ra*32 + ((quad ^ (ra & 3))*8)]);
            bfr[i] = *(const bf16x8*)(&lB[rb*32 + ((quad ^ (rb & 3))*8)]);
        }
        #pragma unroll
        for (int i = 0; i < 4; i++)
            #pragma unroll
            for (int j = 0; j < 4; j++)
                acc[i][j] = __builtin_amdgcn_mfma_f32_16x16x32_bf16(af[i], bfr[j], acc[i][j], 0, 0, 0);
    }

    #pragma unroll
    for (int i = 0; i < 4; i++) {
        int m = m0 + wm*64 + i*16 + quad*4;
        #pragma unroll
        for (int j = 0; j < 4; j++) {
            int n = n0 + wn*64 + j*16 + l16;
            #pragma unroll
            for (int r = 0; r < 4; r++) {
                float y = acc[i][j][r];
                if (n >= act_start) {
                    float bsum = 0.0f;
                    if (n < 8192) bsum = ba[n - 6144];
                    else if (n >= 10240 && n < 10256) bsum = bbeta[n - 10240];
                    y = sigm(y + bsum);
                }
                C[(size_t)(m + r)*N + n] = y;
            }
        }
    }
}

// ---------------- causal depthwise conv (K=4) + silu + scale; writes PACKED [bh][t][dim] ----------------
__global__ void conv_silu_kernel(const float* __restrict__ Y, int col_off,
                                 const float* __restrict__ cw, const float* __restrict__ cb,
                                 float scale, float* __restrict__ out)
{
    int gid = blockIdx.x * blockDim.x + threadIdx.x;  // 32768 total
    int c = gid & 2047;
    int tmp = gid >> 11;
    int tch = tmp & 7;
    int b = tmp >> 3;
    int t0 = tch * 128;
    const float w0 = cw[c*4+0], w1 = cw[c*4+1], w2 = cw[c*4+2], w3 = cw[c*4+3];
    const float bias = cb[c];
    const float* src = Y + (size_t)b*T_*YSTRIDE + col_off + c;
    // packed: out[(b*16+h)*1024*128 + t*128 + dim]
    float* dst = out + (size_t)(b*16 + (c >> 7))*131072 + (c & 127);
    float y0 = (t0 >= 3) ? src[(size_t)(t0-3)*YSTRIDE] : 0.f;
    float y1 = (t0 >= 2) ? src[(size_t)(t0-2)*YSTRIDE] : 0.f;
    float y2 = (t0 >= 1) ? src[(size_t)(t0-1)*YSTRIDE] : 0.f;
    for (int t = t0; t < t0 + 128; t++) {
        float y3 = src[(size_t)t*YSTRIDE];
        float s = fmaf(w0,y0, fmaf(w1,y1, fmaf(w2,y2, fmaf(w3,y3, bias))));
        float r = s * (1.0f/(1.0f + __expf(-s))) * scale;
        dst[(size_t)t*128] = r;
        y0 = y1; y1 = y2; y2 = y3;
    }
}

// ---------------- pack a (sigmoided) and beta out of Y into [bh][t][.] ----------------
__global__ void pack_ab_kernel(const float* __restrict__ Y,
                               float* __restrict__ apack, float* __restrict__ bpack)
{
    int blk = blockIdx.x;
    if (blk < 4096) {
        int gid = blk*256 + threadIdx.x;        // 0..1048575
        int r  = gid >> 9;                      // row 0..2047
        int c4 = gid & 511;                     // float4 col within a-block
        int h = c4 >> 5, dim4 = c4 & 31;
        int b = r >> 10, t = r & 1023;
        float4 f = *(const float4*)(Y + (size_t)r*YSTRIDE + 6144 + c4*4);
        *(float4*)(apack + (size_t)(b*16 + h)*131072 + t*128 + dim4*4) = f;
    } else {
        int gid = (blk - 4096)*256 + threadIdx.x;  // 0..32767
        int r = gid >> 4, h = gid & 15;
        int b = r >> 10, t = r & 1023;
        bpack[(size_t)(b*16 + h)*1024 + t] = Y[(size_t)r*YSTRIDE + 10240 + h];
    }
}

// ---------------- G1 precompute: G1[bh][t] = <k(t), k(t+1)>, G1[.,1023]=0 ----------------
// One 32-lane half per (bh,t): lanes load float4 of k(t),k(t+1), dot, half_sum5, lane31/63 store.
__global__ __launch_bounds__(256) void g1_kernel(const float* __restrict__ k,
                                                 float* __restrict__ g1)
{
    int wave = threadIdx.x >> 6, lane = threadIdx.x & 63;
    int half_id = blockIdx.x*8 + wave*2 + (lane >> 5);   // 0..32767
    int bh = half_id >> 10, t = half_id & 1023;
    const float4* kp = (const float4*)(k + (size_t)bh*131072 + (size_t)t*128) + (lane & 31);
    float4 x = kp[0];
    float4 y = {0.f,0.f,0.f,0.f};
    if (t < 1023) y = kp[32];
    f32x2 d = pkfma((f32x2){x.z,x.w}, (f32x2){y.z,y.w}, (f32x2){x.x,x.y} * (f32x2){y.x,y.y});
    float s = half_sum5(d.x + d.y);
    if ((lane & 31) == 31) g1[(size_t)bh*1024 + t] = s;
}

// ---------------- gated delta recurrence: linearized scan (lag-1) ----------------
// Same proven layout as round 5: lanes 0-31 own row rowA, lanes 32-63 own row
// rowA+64; 4 k-dims/lane (float4); half_sum5 + ds_swizzle(0x03E0) broadcast.
// NEW: the serial chain no longer runs through the reduce. Using
//   sk(t+1) = a(t)*<S(t-1),k(t+1)> - c(t)*G1(t),  G1(t)=<k(t),k(t+1)> (precomputed),
// the chain is c(t) -> 2 fma -> sk(t+1) -> c(t+1); the reduce r=<S(t-1),k(t+1)>
// is issued one full step early, and o(t)=<S(t),q(t)> is entirely off-chain.
// k is consumed at t and t+2, so k runs an A/B(+2-elem X head) rotation issued
// a full 8-step body ahead; other streams keep the 2-group prefetch.
__global__ __launch_bounds__(256) void recurrence_kernel(
    const float* __restrict__ q, const float* __restrict__ k, const float* __restrict__ v,
    const float* __restrict__ a, const float* __restrict__ beta,
    const float* __restrict__ g1, float* __restrict__ o)
{
    const int blk = blockIdx.x;
    const int bh = blk & 31;              // == b*16 + h
    const int rowgrp = blk >> 5;          // 0..15
    const int lane = threadIdx.x & 63;
    const int wave = threadIdx.x >> 6;
    const int rowA = rowgrp*4 + wave;     // 0..63
    const int vrow = (lane < 32) ? rowA : rowA + 64;
    const size_t cb = (size_t)bh * 131072;
    const float4* kp = (const float4*)(k + cb) + (lane & 31);  // step stride 32 float4
    const float4* qp = (const float4*)(q + cb) + (lane & 31);
    const float*  vp = v + cb + vrow;
    const float*  ap = a + cb + vrow;
    const float*  bp = beta + (size_t)bh * 1024;
    const float*  gp = g1 + (size_t)bh * 1024;
    float*        op = o + cb + vrow;

    f32x2 s01 = {0.f, 0.f}, s23 = {0.f, 0.f};
    float sk = 0.f, rprev = 0.f;          // sk(t) and <S(t-1),k(t+1)>; valid lanes 31/63

    float4 kA[4], kB[4], kX[2];           // k groups g, g+1, head of g+2
    float4 qc[4], qn[4];
    float  vc[4], ac[4], bc[4], gc[4], vn[4], an[4], bn[4], gn[4];

    #pragma unroll
    for (int j = 0; j < 4; j++) {
        kA[j] = kp[j*32]; kB[j] = kp[(4+j)*32];
        qc[j] = qp[j*32]; qn[j] = qp[(4+j)*32];
        vc[j] = vp[j*128]; ac[j] = ap[j*128]; bc[j] = bp[j]; gc[j] = gp[j];
        vn[j] = vp[(4+j)*128]; an[j] = ap[(4+j)*128]; bn[j] = bp[4+j]; gn[j] = gp[4+j];
    }
    kX[0] = kp[8*32]; kX[1] = kp[9*32];

// kv = k(t); kv2 = k(t+2); chain: c_ -> sk fixup (2 fma). All else off-chain.
#define RSTEP(kv, kv2, qv, vt, at, bt, gt, oidx) { \
    float c_ = (bt) * (sk - (vt)); \
    sk = fmaf((at), rprev, -(c_ * (gt))); \
    float cl = __builtin_bit_cast(float, __builtin_amdgcn_ds_swizzle(__builtin_bit_cast(int, c_), 0x03E0)); \
    f32x2 k01 = {(kv).x, (kv).y}, k23 = {(kv).z, (kv).w}; \
    f32x2 c2 = {cl, cl}; \
    f32x2 a2 = {(at), (at)}; \
    s01 = pkfma(a2, s01, -(c2*k01)); \
    s23 = pkfma(a2, s23, -(c2*k23)); \
    f32x2 q01 = {(qv).x, (qv).y}, q23 = {(qv).z, (qv).w}; \
    f32x2 o2 = pkfma(s23, q23, s01*q01); \
    float ov_ = half_sum5(o2.x + o2.y); \
    if ((lane & 31) == 31) op[(size_t)(oidx)*128] = ov_; \
    f32x2 x01 = {(kv2).x, (kv2).y}, x23 = {(kv2).z, (kv2).w}; \
    f32x2 r2 = pkfma(s23, x23, s01*x01); \
    rprev = half_sum5(r2.x + r2.y); \
}

    #pragma unroll 1
    for (int t0 = 0; t0 < T_; t0 += 8) {
        // compute group c: t = t0..t0+3 (k(t+2): kA[2],kA[3],kB[0],kB[1])
        RSTEP(kA[0], kA[2], qc[0], vc[0], ac[0], bc[0], gc[0], t0+0)
        RSTEP(kA[1], kA[3], qc[1], vc[1], ac[1], bc[1], gc[1], t0+1)
        RSTEP(kA[2], kB[0], qc[2], vc[2], ac[2], bc[2], gc[2], t0+2)
        RSTEP(kA[3], kB[1], qc[3], vc[3], ac[3], bc[3], gc[3], t0+3)
        // reload A <- t0+8..11; c-streams <- t0+8..11 (last body overruns into
        // adjacent ws arrays; values in-bounds of ws, never used)
        #pragma unroll
        for (int j = 0; j < 4; j++) {
            int t = t0 + 8 + j;
            kA[j] = kp[t*32]; qc[j] = qp[t*32];
            vc[j] = vp[(size_t)t*128]; ac[j] = ap[(size_t)t*128]; bc[j] = bp[t]; gc[j] = gp[t];
        }
        // compute group n: t = t0+4..t0+7 (k(t+2): kB[2],kB[3],kX[0],kX[1])
        RSTEP(kB[0], kB[2], qn[0], vn[0], an[0], bn[0], gn[0], t0+4)
        RSTEP(kB[1], kB[3], qn[1], vn[1], an[1], bn[1], gn[1], t0+5)
        RSTEP(kB[2], kX[0], qn[2], vn[2], an[2], bn[2], gn[2], t0+6)
        RSTEP(kB[3], kX[1], qn[3], vn[3], an[3], bn[3], gn[3], t0+7)
        // reload B <- t0+12..15, X <- k(t0+16..17); n-streams <- t0+12..15
        #pragma unroll
        for (int j = 0; j < 4; j++) {
            int t = t0 + 12 + j;
            kB[j] = kp[t*32]; qn[j] = qp[t*32];
            vn[j] = vp[(size_t)t*128]; an[j] = ap[(size_t)t*128]; bn[j] = bp[t]; gn[j] = gp[t];
        }
        kX[0] = kp[(t0+16)*32]; kX[1] = kp[(t0+17)*32];
    }
#undef RSTEP
}

// ---------------- LayerNorm over DV, * gate, -> bf16 (reads packed ov) ----------------
__global__ __launch_bounds__(256) void ln_gate_kernel(
    const float* __restrict__ o, const float* __restrict__ g, int g_stride,
    const float* __restrict__ ln_g, const float* __restrict__ ln_b,
    unsigned short* __restrict__ og)
{
    int wave = threadIdx.x >> 6, lane = threadIdx.x & 63;
    int gidx = blockIdx.x*4 + wave;     // 0..32767
    int row = gidx >> 4, h = gidx & 15;
    int b = row >> 10, t = row & 1023;
    const float* ob = o + (size_t)(b*16 + h)*131072 + (size_t)t*128;
    int d0 = lane*2;
    float2 xv = *(const float2*)(ob + d0);
    float s = xv.x + xv.y, ss = xv.x*xv.x + xv.y*xv.y;
    for (int m = 1; m < 64; m <<= 1) { s += __shfl_xor(s, m); ss += __shfl_xor(ss, m); }
    float mu  = s * (1.f/128.f);
    float var = ss * (1.f/128.f) - mu*mu;
    float inv = rsqrtf(var + 1e-5f);
    const float* gb = g + (size_t)row*g_stride + h*128;
    float r0 = ((xv.x - mu)*inv*ln_g[d0]   + ln_b[d0])   * gb[d0];
    float r1 = ((xv.y - mu)*inv*ln_g[d0+1] + ln_b[d0+1]) * gb[d0+1];
    ushort2 u; u.x = f2bf(r0); u.y = f2bf(r1);
    *(ushort2*)(og + (size_t)row*2048 + h*128 + d0) = u;
}

extern "C" void kernel_launch(void* const* d_in, const int* in_sizes, int n_in,
                              void* d_out, int out_size, void* d_ws, size_t ws_size,
                              hipStream_t stream)
{
    const float* x   = (const float*)d_in[0];
    const float* Wq  = (const float*)d_in[1];
    const float* Wk  = (const float*)d_in[2];
    const float* Wv  = (const float*)d_in[3];
    const float* Wa  = (const float*)d_in[4];
    const float* ba  = (const float*)d_in[5];
    const float* Wb  = (const float*)d_in[6];
    const float* bb  = (const float*)d_in[7];
    const float* cqw = (const float*)d_in[8];
    const float* cqb = (const float*)d_in[9];
    const float* ckw = (const float*)d_in[10];
    const float* ckb = (const float*)d_in[11];
    const float* cvw = (const float*)d_in[12];
    const float* cvb = (const float*)d_in[13];
    const float* Wg  = (const float*)d_in[14];
    const float* lng = (const float*)d_in[15];
    const float* lnb = (const float*)d_in[16];
    const float* Wo  = (const float*)d_in[17];
    float* out = (float*)d_out;

    char* ws = (char*)d_ws;
    size_t off = 0;
    auto alloc = [&](size_t bytes){ void* p = ws + off; off += (bytes + 255) & ~(size_t)255; return p; };
    unsigned short* xb   = (unsigned short*)alloc((size_t)ROWS*D_*2);   // reused as og
    unsigned short* Wcat = (unsigned short*)alloc((size_t)NCAT*D_*2);   // reused as apack/bpack/g1 after gemm1
    unsigned short* Wob  = (unsigned short*)alloc((size_t)D_*D_*2);
    float* Y  = (float*)alloc((size_t)ROWS*YSTRIDE*4);
    float* qs = (float*)alloc((size_t)ROWS*2048*4);   // packed [bh][t][128]
    float* ks = (float*)alloc((size_t)ROWS*2048*4);   // packed
    float* vs = (float*)alloc((size_t)ROWS*2048*4);   // packed
    float* ov = (float*)alloc((size_t)ROWS*2048*4);   // packed
    unsigned short* og = xb;
    float* apack = (float*)Wcat;                       // 16MB, alias (Wcat dead after gemm1)
    float* bpack = apack + (size_t)32*1024*128;        // 128KB
    float* g1    = bpack + (size_t)32*1024;            // 128KB, still within Wcat
    (void)ws_size;

    Cast8 cargs;
    cargs.p[0]=x; cargs.p[1]=Wq; cargs.p[2]=Wk; cargs.p[3]=Wv; cargs.p[4]=Wa;
    cargs.p[5]=Wg; cargs.p[6]=Wo; cargs.p[7]=Wb;
    cast_all_kernel<<<28928, 256, 0, stream>>>(cargs, xb, Wcat, Wob);

    // fused projections + beta: [2048,10368] = xb @ Wcat^T
    gemm_bt<<<dim3(81,16), 256, 0, stream>>>(xb, Wcat, Y, ROWS, NCAT, D_, 6144, ba, bb);

    // pack a/beta into [bh][t][.] (overwrites Wcat region -- gemm1 already done)
    pack_ab_kernel<<<4224, 256, 0, stream>>>(Y, apack, bpack);

    const float kscale = 0.08838834764831845f;  // DK^-0.5
    conv_silu_kernel<<<128, 256, 0, stream>>>(Y, 0,    cqw, cqb, 1.0f,   qs);
    conv_silu_kernel<<<128, 256, 0, stream>>>(Y, 2048, ckw, ckb, kscale, ks);
    conv_silu_kernel<<<128, 256, 0, stream>>>(Y, 4096, cvw, cvb, 1.0f,   vs);

    // G1(t) = <k(t),k(t+1)> per (bh,t)
    g1_kernel<<<4096, 256, 0, stream>>>(ks, g1);

    // 512 blocks x 4 waves; each wave: 2 v-rows (lane halves)
    recurrence_kernel<<<512, 256, 0, stream>>>(qs, ks, vs, apack, bpack, g1, ov);

    ln_gate_kernel<<<8192, 256, 0, stream>>>(ov, Y + 8192, YSTRIDE, lng, lnb, og);

    gemm_bt<<<dim3(16,16), 256, 0, stream>>>(og, Wob, out, ROWS, D_, D_, 1<<30, nullptr, nullptr);
}

// Round 7
// 640.017 us; speedup vs baseline: 1.3162x; 1.0556x over previous
//
#include <hip/hip_runtime.h>
#include <hip/hip_bf16.h>
#include <cstdint>
#include <cstddef>

#define B_ 2
#define T_ 1024
#define D_ 2048
#define H_ 16
#define DK_ 128
#define DV_ 128
#define ROWS (B_*T_)      // 2048
// Y columns: [q 0:2048 | k 2048:4096 | v 4096:6144 | a 6144:8192 | g 8192:10240 | beta 10240:10256 | pad :10368]
#define NCAT 10368
#define YSTRIDE 10368

typedef __attribute__((ext_vector_type(8))) short bf16x8;
typedef __attribute__((ext_vector_type(4))) float f32x4;
typedef __attribute__((ext_vector_type(2))) float f32x2;

__device__ inline unsigned short f2bf(float f){
    union { float f; unsigned int u; } v; v.f = f;
    unsigned int r = (v.u + 0x7fffu + ((v.u >> 16) & 1u)) >> 16;
    return (unsigned short)r;
}
__device__ inline float sigm(float x){ return 1.0f / (1.0f + __expf(-x)); }

// ---- DPP helpers (PROVEN rounds 0/1/5/6) ----
template<int CTRL>
__device__ __forceinline__ float dpp_add(float x){
    int t = __builtin_amdgcn_update_dpp(0, __builtin_bit_cast(int, x), CTRL, 0xf, 0xf, true);
    return x + __builtin_bit_cast(float, t);
}
// Sum within each 32-lane half. After 5 stages:
//   lane31 = sum(lanes 0..31), lane63 = sum(lanes 32..63). Other lanes partial.
__device__ __forceinline__ float half_sum5(float x){
    x = dpp_add<0x111>(x);   // row_shr:1
    x = dpp_add<0x112>(x);   // row_shr:2
    x = dpp_add<0x114>(x);   // row_shr:4
    x = dpp_add<0x118>(x);   // row_shr:8   lane15/31/47/63 = 16-sums
    x = dpp_add<0x142>(x);   // row_bcast15 lane31 = sum(0..31), lane63 = sum(32..63)
    return x;
}

__device__ __forceinline__ f32x2 pkfma(f32x2 a, f32x2 b, f32x2 c){
    return __builtin_elementwise_fma(a, b, c);
}

__device__ __forceinline__ void gl2lds16(const void* g, void* l){
    __builtin_amdgcn_global_load_lds((const __attribute__((address_space(1))) void*)g,
                                     (__attribute__((address_space(3))) void*)l, 16, 0, 0);
}

// ---------------- fused fp32 -> bf16 casts (one launch) ----------------
struct Cast8 { const float* p[8]; };  // x, Wq, Wk, Wv, Wa, Wg, Wo, Wb
__global__ void cast_all_kernel(Cast8 args, unsigned short* __restrict__ xb,
                                unsigned short* __restrict__ Wcat,
                                unsigned short* __restrict__ Wob){
    int blk = blockIdx.x;
    if (blk >= 28704) {  // zero-pad rows 10256..10367 of Wcat
        int i = (blk - 28704)*1024 + threadIdx.x*4;
        *(ushort4*)(Wcat + (size_t)10256*2048 + i) = (ushort4){0,0,0,0};
        return;
    }
    const float* src; unsigned short* dst; int i;
    if (blk >= 28672) {  // Wb -> Wcat rows 10240..10255
        i = (blk - 28672)*1024 + threadIdx.x*4;
        src = args.p[7]; dst = Wcat + (size_t)10240*2048;
    } else {
        int seg = blk >> 12;
        i = (blk & 4095)*1024 + threadIdx.x*4;
        src = args.p[seg];
        if (seg == 0)      dst = xb;
        else if (seg <= 5) dst = Wcat + (size_t)(seg-1)*4194304;
        else               dst = Wob;
    }
    float4 f = *(const float4*)(src + i);
    ushort4 u; u.x = f2bf(f.x); u.y = f2bf(f.y); u.z = f2bf(f.z); u.w = f2bf(f.w);
    *(ushort4*)(dst + i) = u;
}

// ---------------- bf16 GEMM (m97-style): C[M,N] = A[M,K]*Bm[N,K]^T ----------------
__global__ __launch_bounds__(256) void gemm_bt(
    const unsigned short* __restrict__ A,
    const unsigned short* __restrict__ Bm,
    float* __restrict__ C, int M, int N, int K,
    int act_start, const float* __restrict__ ba, const float* __restrict__ bbeta)
{
    __shared__ __align__(16) unsigned short lA[128*32];
    __shared__ __align__(16) unsigned short lB[128*32];
    const int tid  = threadIdx.x;
    const int wave = tid >> 6, lane = tid & 63;
    const int quad = lane >> 4, l16 = lane & 15;
    const int wm = wave >> 1, wn = wave & 1;
    const int m0 = blockIdx.y * 128, n0 = blockIdx.x * 128;

    const unsigned short* gsrcA[2];
    const unsigned short* gsrcB[2];
    unsigned short* ldst[2];
    #pragma unroll
    for (int i = 0; i < 2; i++) {
        int chunk = wave*128 + i*64 + lane;
        int r = chunk >> 2, p = chunk & 3;
        int gcb = p ^ (r & 3);
        gsrcA[i] = A  + (size_t)(m0 + r)*K + gcb*8;
        gsrcB[i] = Bm + (size_t)(n0 + r)*K + gcb*8;
        ldst[i]  = (unsigned short*)((char*)lA + (size_t)(wave*128 + i*64)*16);
    }
    const size_t lBoff = (size_t)((char*)lB - (char*)lA);

    f32x4 acc[4][4];
    #pragma unroll
    for (int i = 0; i < 4; i++)
        #pragma unroll
        for (int j = 0; j < 4; j++) acc[i][j] = (f32x4){0.f,0.f,0.f,0.f};

    for (int k0 = 0; k0 < K; k0 += 32) {
        __syncthreads();
        #pragma unroll
        for (int i = 0; i < 2; i++) {
            gl2lds16(gsrcA[i] + k0, ldst[i]);
            gl2lds16(gsrcB[i] + k0, (char*)ldst[i] + lBoff);
        }
        __syncthreads();
        bf16x8 af[4], bfr[4];
        #pragma unroll
        for (int i = 0; i < 4; i++) {
            int ra = wm*64 + i*16 + l16;
            int rb = wn*64 + i*16 + l16;
            af[i]  = *(const bf16x8*)(&lA[ra*32 + ((quad ^ (ra & 3))*8)]);
            bfr[i] = *(const bf16x8*)(&lB[rb*32 + ((quad ^ (rb & 3))*8)]);
        }
        #pragma unroll
        for (int i = 0; i < 4; i++)
            #pragma unroll
            for (int j = 0; j < 4; j++)
                acc[i][j] = __builtin_amdgcn_mfma_f32_16x16x32_bf16(af[i], bfr[j], acc[i][j], 0, 0, 0);
    }

    #pragma unroll
    for (int i = 0; i < 4; i++) {
        int m = m0 + wm*64 + i*16 + quad*4;
        #pragma unroll
        for (int j = 0; j < 4; j++) {
            int n = n0 + wn*64 + j*16 + l16;
            #pragma unroll
            for (int r = 0; r < 4; r++) {
                float y = acc[i][j][r];
                if (n >= act_start) {
                    float bsum = 0.0f;
                    if (n < 8192) bsum = ba[n - 6144];
                    else if (n >= 10240 && n < 10256) bsum = bbeta[n - 10240];
                    y = sigm(y + bsum);
                }
                C[(size_t)(m + r)*N + n] = y;
            }
        }
    }
}

// ---------------- FUSED causal depthwise conv (K=4) + silu + scale for q,k,v ----------------
// 768 blocks (3 blocks/CU) instead of 3 sequential 128-block launches.
// which = conv id (block-uniform); t-chunks of 64; writes PACKED [bh][t][dim].
struct ConvAll { const float* w[3]; const float* bia[3]; float scale[3]; };
__global__ __launch_bounds__(256) void conv_silu_kernel(const float* __restrict__ Y, ConvAll ca,
                                 float* __restrict__ qs, float* __restrict__ ks,
                                 float* __restrict__ vs)
{
    int gid = blockIdx.x * 256 + threadIdx.x;   // 0..196607
    int which = gid >> 16;                      // 0..2 (block-uniform: 256 blocks per conv)
    int sub = gid & 65535;
    int c = sub & 2047;
    int tmp = sub >> 11;                        // 0..31
    int tch = tmp & 15;                         // 16 chunks of 64
    int b = tmp >> 4;
    int t0 = tch * 64;
    const float* cw = ca.w[which];
    const float w0 = cw[c*4+0], w1 = cw[c*4+1], w2 = cw[c*4+2], w3 = cw[c*4+3];
    const float bias = ca.bia[which][c];
    const float scale = ca.scale[which];
    const float* src = Y + (size_t)b*T_*YSTRIDE + which*2048 + c;
    float* outbase = (which == 0) ? qs : (which == 1) ? ks : vs;
    float* dst = outbase + (size_t)(b*16 + (c >> 7))*131072 + (c & 127);
    float y0 = (t0 >= 3) ? src[(size_t)(t0-3)*YSTRIDE] : 0.f;
    float y1 = (t0 >= 2) ? src[(size_t)(t0-2)*YSTRIDE] : 0.f;
    float y2 = (t0 >= 1) ? src[(size_t)(t0-1)*YSTRIDE] : 0.f;
    for (int t = t0; t < t0 + 64; t++) {
        float y3 = src[(size_t)t*YSTRIDE];
        float s = fmaf(w0,y0, fmaf(w1,y1, fmaf(w2,y2, fmaf(w3,y3, bias))));
        float r = s * (1.0f/(1.0f + __expf(-s))) * scale;
        dst[(size_t)t*128] = r;
        y0 = y1; y1 = y2; y2 = y3;
    }
}

// ---------------- pack a (sigmoided) and beta out of Y into [bh][t][.] ----------------
__global__ void pack_ab_kernel(const float* __restrict__ Y,
                               float* __restrict__ apack, float* __restrict__ bpack)
{
    int blk = blockIdx.x;
    if (blk < 4096) {
        int gid = blk*256 + threadIdx.x;        // 0..1048575
        int r  = gid >> 9;                      // row 0..2047
        int c4 = gid & 511;                     // float4 col within a-block
        int h = c4 >> 5, dim4 = c4 & 31;
        int b = r >> 10, t = r & 1023;
        float4 f = *(const float4*)(Y + (size_t)r*YSTRIDE + 6144 + c4*4);
        *(float4*)(apack + (size_t)(b*16 + h)*131072 + t*128 + dim4*4) = f;
    } else {
        int gid = (blk - 4096)*256 + threadIdx.x;  // 0..32767
        int r = gid >> 4, h = gid & 15;
        int b = r >> 10, t = r & 1023;
        bpack[(size_t)(b*16 + h)*1024 + t] = Y[(size_t)r*YSTRIDE + 10240 + h];
    }
}

// ---------------- G1/G2 precompute: G1[bh][t]=<k(t),k(t+1)>, G2[bh][t]=<k(t),k(t+2)>; 0 at tail ----
__global__ __launch_bounds__(256) void g12_kernel(const float* __restrict__ k,
                                                  float* __restrict__ g1, float* __restrict__ g2)
{
    int wave = threadIdx.x >> 6, lane = threadIdx.x & 63;
    int half_id = blockIdx.x*8 + wave*2 + (lane >> 5);   // 0..32767
    int bh = half_id >> 10, t = half_id & 1023;
    const float4* kp = (const float4*)(k + (size_t)bh*131072 + (size_t)t*128) + (lane & 31);
    float4 x = kp[0];
    float4 y1 = {0.f,0.f,0.f,0.f}, y2 = {0.f,0.f,0.f,0.f};
    if (t < 1023) y1 = kp[32];
    if (t < 1022) y2 = kp[64];
    f32x2 d1 = pkfma((f32x2){x.z,x.w}, (f32x2){y1.z,y1.w}, (f32x2){x.x,x.y} * (f32x2){y1.x,y1.y});
    f32x2 d2 = pkfma((f32x2){x.z,x.w}, (f32x2){y2.z,y2.w}, (f32x2){x.x,x.y} * (f32x2){y2.x,y2.y});
    float s1 = half_sum5(d1.x + d1.y);
    float s2 = half_sum5(d2.x + d2.y);
    if ((lane & 31) == 31) { g1[(size_t)bh*1024 + t] = s1; g2[(size_t)bh*1024 + t] = s2; }
}

// ---------------- gated delta recurrence: lag-2 linearized scan ----------------
// Proven layout (rounds 5/6): lanes 0-31 row rowA, lanes 32-63 row rowA+64;
// float4 k-dims/lane; half_sum5 + ds_swizzle(0x03E0) broadcast.
// Lag-2 chain:  rr(t) = <S(t),k(t+3)>  (long path, produced at step t, consumed
// at step t+2)  ->  P(t) = a(t-1)*rr(t-2) - c(t-1)*G2(t-1)  ->
// sk(t+1) = a(t)*P(t) - c(t)*G1(t).  The c->c chain is 3 VALU ops; the
// swizzle+S-update+dot+reduce long path now has a TWO-step window (round 6's
// lag-1 only had ~1 step -- that was the miss).
__global__ __launch_bounds__(256) void recurrence_kernel(
    const float* __restrict__ q, const float* __restrict__ k, const float* __restrict__ v,
    const float* __restrict__ a, const float* __restrict__ beta,
    const float* __restrict__ g1, const float* __restrict__ g2, float* __restrict__ o)
{
    const int blk = blockIdx.x;
    const int bh = blk & 31;              // == b*16 + h
    const int rowgrp = blk >> 5;          // 0..15
    const int lane = threadIdx.x & 63;
    const int wave = threadIdx.x >> 6;
    const int rowA = rowgrp*4 + wave;     // 0..63
    const int vrow = (lane < 32) ? rowA : rowA + 64;
    const size_t cb = (size_t)bh * 131072;
    const float4* kp = (const float4*)(k + cb) + (lane & 31);  // step stride 32 float4
    const float4* qp = (const float4*)(q + cb) + (lane & 31);
    const float*  vp = v + cb + vrow;
    const float*  ap = a + cb + vrow;
    const float*  bp = beta + (size_t)bh * 1024;
    const float*  g1p = g1 + (size_t)bh * 1024;
    const float*  g2p = g2 + (size_t)bh * 1024;
    float*        op = o + cb + vrow;

    f32x2 s01 = {0.f, 0.f}, s23 = {0.f, 0.f};
    // scalar pipeline (valid in lanes 31/63):
    float sk = 0.f, c_prev = 0.f, a_prev = 0.f, g2_prev = 0.f;
    float rr_old = 0.f, rr_prev = 0.f;    // rr(t-2), rr(t-1)

    float4 kA[4], kB[4], kX[3];           // k: groups g, g+1, head(3) of g+2
    float4 qc[4], qn[4];
    float  vc[4], ac[4], bc[4], h1c[4], h2c[4];
    float  vn[4], an[4], bn[4], h1n[4], h2n[4];

    #pragma unroll
    for (int j = 0; j < 4; j++) {
        kA[j] = kp[j*32]; kB[j] = kp[(4+j)*32];
        qc[j] = qp[j*32]; qn[j] = qp[(4+j)*32];
        vc[j] = vp[j*128]; ac[j] = ap[j*128]; bc[j] = bp[j];
        h1c[j] = g1p[j]; h2c[j] = g2p[j];
        vn[j] = vp[(4+j)*128]; an[j] = ap[(4+j)*128]; bn[j] = bp[4+j];
        h1n[j] = g1p[4+j]; h2n[j] = g2p[4+j];
    }
    kX[0] = kp[8*32]; kX[1] = kp[9*32]; kX[2] = kp[10*32];

// kv = k(t); kv3 = k(t+3).  Scalar chain: c_ -> sk (1 fma).  P off-chain
// (one-step-old inputs).  Long path (swizzle->S->rr dot->reduce) has 2 steps.
#define RSTEP(kv, kv3, qv, vt, at, bt, g1t, g2t, oidx) { \
    float P = fmaf(a_prev, rr_old, -(c_prev * (g2_prev))); \
    float c_ = (bt) * (sk - (vt)); \
    sk = fmaf((at), P, -(c_ * (g1t))); \
    a_prev = (at); c_prev = c_; g2_prev = (g2t); \
    float cl = __builtin_bit_cast(float, __builtin_amdgcn_ds_swizzle(__builtin_bit_cast(int, c_), 0x03E0)); \
    f32x2 k01 = {(kv).x, (kv).y}, k23 = {(kv).z, (kv).w}; \
    f32x2 c2 = {cl, cl}; \
    f32x2 a2 = {(at), (at)}; \
    s01 = pkfma(a2, s01, -(c2*k01)); \
    s23 = pkfma(a2, s23, -(c2*k23)); \
    f32x2 q01 = {(qv).x, (qv).y}, q23 = {(qv).z, (qv).w}; \
    f32x2 o2 = pkfma(s23, q23, s01*q01); \
    float ov_ = half_sum5(o2.x + o2.y); \
    if ((lane & 31) == 31) op[(size_t)(oidx)*128] = ov_; \
    f32x2 x01 = {(kv3).x, (kv3).y}, x23 = {(kv3).z, (kv3).w}; \
    f32x2 r2 = pkfma(s23, x23, s01*x01); \
    float rr_new = half_sum5(r2.x + r2.y); \
    rr_old = rr_prev; rr_prev = rr_new; \
}

    #pragma unroll 1
    for (int t0 = 0; t0 < T_; t0 += 8) {
        // compute group c: t = t0..t0+3  (k(t+3): kA[3], kB[0], kB[1], kB[2])
        RSTEP(kA[0], kA[3], qc[0], vc[0], ac[0], bc[0], h1c[0], h2c[0], t0+0)
        RSTEP(kA[1], kB[0], qc[1], vc[1], ac[1], bc[1], h1c[1], h2c[1], t0+1)
        RSTEP(kA[2], kB[1], qc[2], vc[2], ac[2], bc[2], h1c[2], h2c[2], t0+2)
        RSTEP(kA[3], kB[2], qc[3], vc[3], ac[3], bc[3], h1c[3], h2c[3], t0+3)
        // reload A <- t0+8..11; c-streams <- t0+8..11 (last body overruns into
        // adjacent ws arrays; values in-bounds of ws, never consumed)
        #pragma unroll
        for (int j = 0; j < 4; j++) {
            int t = t0 + 8 + j;
            kA[j] = kp[t*32]; qc[j] = qp[t*32];
            vc[j] = vp[(size_t)t*128]; ac[j] = ap[(size_t)t*128]; bc[j] = bp[t];
            h1c[j] = g1p[t]; h2c[j] = g2p[t];
        }
        // compute group n: t = t0+4..t0+7  (k(t+3): kB[3], kX[0], kX[1], kX[2])
        RSTEP(kB[0], kB[3], qn[0], vn[0], an[0], bn[0], h1n[0], h2n[0], t0+4)
        RSTEP(kB[1], kX[0], qn[1], vn[1], an[1], bn[1], h1n[1], h2n[1], t0+5)
        RSTEP(kB[2], kX[1], qn[2], vn[2], an[2], bn[2], h1n[2], h2n[2], t0+6)
        RSTEP(kB[3], kX[2], qn[3], vn[3], an[3], bn[3], h1n[3], h2n[3], t0+7)
        // reload B <- t0+12..15, X <- k(t0+16..18); n-streams <- t0+12..15
        #pragma unroll
        for (int j = 0; j < 4; j++) {
            int t = t0 + 12 + j;
            kB[j] = kp[t*32]; qn[j] = qp[t*32];
            vn[j] = vp[(size_t)t*128]; an[j] = ap[(size_t)t*128]; bn[j] = bp[t];
            h1n[j] = g1p[t]; h2n[j] = g2p[t];
        }
        kX[0] = kp[(t0+16)*32]; kX[1] = kp[(t0+17)*32]; kX[2] = kp[(t0+18)*32];
    }
#undef RSTEP
}

// ---------------- LayerNorm over DV, * gate, -> bf16 (reads packed ov) ----------------
__global__ __launch_bounds__(256) void ln_gate_kernel(
    const float* __restrict__ o, const float* __restrict__ g, int g_stride,
    const float* __restrict__ ln_g, const float* __restrict__ ln_b,
    unsigned short* __restrict__ og)
{
    int wave = threadIdx.x >> 6, lane = threadIdx.x & 63;
    int gidx = blockIdx.x*4 + wave;     // 0..32767
    int row = gidx >> 4, h = gidx & 15;
    int b = row >> 10, t = row & 1023;
    const float* ob = o + (size_t)(b*16 + h)*131072 + (size_t)t*128;
    int d0 = lane*2;
    float2 xv = *(const float2*)(ob + d0);
    float s = xv.x + xv.y, ss = xv.x*xv.x + xv.y*xv.y;
    for (int m = 1; m < 64; m <<= 1) { s += __shfl_xor(s, m); ss += __shfl_xor(ss, m); }
    float mu  = s * (1.f/128.f);
    float var = ss * (1.f/128.f) - mu*mu;
    float inv = rsqrtf(var + 1e-5f);
    const float* gb = g + (size_t)row*g_stride + h*128;
    float r0 = ((xv.x - mu)*inv*ln_g[d0]   + ln_b[d0])   * gb[d0];
    float r1 = ((xv.y - mu)*inv*ln_g[d0+1] + ln_b[d0+1]) * gb[d0+1];
    ushort2 u; u.x = f2bf(r0); u.y = f2bf(r1);
    *(ushort2*)(og + (size_t)row*2048 + h*128 + d0) = u;
}

extern "C" void kernel_launch(void* const* d_in, const int* in_sizes, int n_in,
                              void* d_out, int out_size, void* d_ws, size_t ws_size,
                              hipStream_t stream)
{
    const float* x   = (const float*)d_in[0];
    const float* Wq  = (const float*)d_in[1];
    const float* Wk  = (const float*)d_in[2];
    const float* Wv  = (const float*)d_in[3];
    const float* Wa  = (const float*)d_in[4];
    const float* ba  = (const float*)d_in[5];
    const float* Wb  = (const float*)d_in[6];
    const float* bb  = (const float*)d_in[7];
    const float* cqw = (const float*)d_in[8];
    const float* cqb = (const float*)d_in[9];
    const float* ckw = (const float*)d_in[10];
    const float* ckb = (const float*)d_in[11];
    const float* cvw = (const float*)d_in[12];
    const float* cvb = (const float*)d_in[13];
    const float* Wg  = (const float*)d_in[14];
    const float* lng = (const float*)d_in[15];
    const float* lnb = (const float*)d_in[16];
    const float* Wo  = (const float*)d_in[17];
    float* out = (float*)d_out;

    char* ws = (char*)d_ws;
    size_t off = 0;
    auto alloc = [&](size_t bytes){ void* p = ws + off; off += (bytes + 255) & ~(size_t)255; return p; };
    unsigned short* xb   = (unsigned short*)alloc((size_t)ROWS*D_*2);   // reused as og
    unsigned short* Wcat = (unsigned short*)alloc((size_t)NCAT*D_*2);   // reused as apack/bpack/g1/g2 after gemm1
    unsigned short* Wob  = (unsigned short*)alloc((size_t)D_*D_*2);
    float* Y  = (float*)alloc((size_t)ROWS*YSTRIDE*4);
    float* qs = (float*)alloc((size_t)ROWS*2048*4);   // packed [bh][t][128]
    float* ks = (float*)alloc((size_t)ROWS*2048*4);   // packed
    float* vs = (float*)alloc((size_t)ROWS*2048*4);   // packed
    float* ov = (float*)alloc((size_t)ROWS*2048*4);   // packed
    unsigned short* og = xb;
    float* apack = (float*)Wcat;                       // 16MB, alias (Wcat dead after gemm1)
    float* bpack = apack + (size_t)32*1024*128;        // 128KB
    float* g1    = bpack + (size_t)32*1024;            // 128KB
    float* g2    = g1    + (size_t)32*1024;            // 128KB, still within Wcat (40.5MB)
    (void)ws_size;

    Cast8 cargs;
    cargs.p[0]=x; cargs.p[1]=Wq; cargs.p[2]=Wk; cargs.p[3]=Wv; cargs.p[4]=Wa;
    cargs.p[5]=Wg; cargs.p[6]=Wo; cargs.p[7]=Wb;
    cast_all_kernel<<<28928, 256, 0, stream>>>(cargs, xb, Wcat, Wob);

    // fused projections + beta: [2048,10368] = xb @ Wcat^T
    gemm_bt<<<dim3(81,16), 256, 0, stream>>>(xb, Wcat, Y, ROWS, NCAT, D_, 6144, ba, bb);

    // pack a/beta into [bh][t][.] (overwrites Wcat region -- gemm1 already done)
    pack_ab_kernel<<<4224, 256, 0, stream>>>(Y, apack, bpack);

    // fused q/k/v causal conv + silu (+ k scale), one launch, 3 blocks/CU
    const float kscale = 0.08838834764831845f;  // DK^-0.5
    ConvAll ca;
    ca.w[0]=cqw; ca.w[1]=ckw; ca.w[2]=cvw;
    ca.bia[0]=cqb; ca.bia[1]=ckb; ca.bia[2]=cvb;
    ca.scale[0]=1.0f; ca.scale[1]=kscale; ca.scale[2]=1.0f;
    conv_silu_kernel<<<768, 256, 0, stream>>>(Y, ca, qs, ks, vs);

    // G1(t)=<k(t),k(t+1)>, G2(t)=<k(t),k(t+2)> per (bh,t)
    g12_kernel<<<4096, 256, 0, stream>>>(ks, g1, g2);

    // 512 blocks x 4 waves; each wave: 2 v-rows (lane halves)
    recurrence_kernel<<<512, 256, 0, stream>>>(qs, ks, vs, apack, bpack, g1, g2, ov);

    ln_gate_kernel<<<8192, 256, 0, stream>>>(ov, Y + 8192, YSTRIDE, lng, lnb, og);

    gemm_bt<<<dim3(16,16), 256, 0, stream>>>(og, Wob, out, ROWS, D_, D_, 1<<30, nullptr, nullptr);
}

// Round 8
// 606.041 us; speedup vs baseline: 1.3900x; 1.0561x over previous
//
#include <hip/hip_runtime.h>
#include <hip/hip_bf16.h>
#include <cstdint>
#include <cstddef>

#define B_ 2
#define T_ 1024
#define D_ 2048
#define H_ 16
#define DK_ 128
#define DV_ 128
#define ROWS (B_*T_)      // 2048
// Y columns: [q 0:2048 | k 2048:4096 | v 4096:6144 | a 6144:8192 | g 8192:10240 | beta 10240:10256 | pad :10368]
#define NCAT 10368
#define YSTRIDE 10368

typedef __attribute__((ext_vector_type(8))) short bf16x8;
typedef __attribute__((ext_vector_type(4))) float f32x4;
typedef __attribute__((ext_vector_type(2))) float f32x2;

__device__ inline unsigned short f2bf(float f){
    union { float f; unsigned int u; } v; v.f = f;
    unsigned int r = (v.u + 0x7fffu + ((v.u >> 16) & 1u)) >> 16;
    return (unsigned short)r;
}
__device__ inline float sigm(float x){ return 1.0f / (1.0f + __expf(-x)); }

// ---- DPP helpers (PROVEN rounds 0/1/5/6) ----
template<int CTRL>
__device__ __forceinline__ float dpp_add(float x){
    int t = __builtin_amdgcn_update_dpp(0, __builtin_bit_cast(int, x), CTRL, 0xf, 0xf, true);
    return x + __builtin_bit_cast(float, t);
}
// Sum within each 32-lane half. After 5 stages:
//   lane31 = sum(lanes 0..31), lane63 = sum(lanes 32..63). Other lanes partial.
__device__ __forceinline__ float half_sum5(float x){
    x = dpp_add<0x111>(x);   // row_shr:1
    x = dpp_add<0x112>(x);   // row_shr:2
    x = dpp_add<0x114>(x);   // row_shr:4
    x = dpp_add<0x118>(x);   // row_shr:8   lane15/31/47/63 = 16-sums
    x = dpp_add<0x142>(x);   // row_bcast15 lane31 = sum(0..31), lane63 = sum(32..63)
    return x;
}

__device__ __forceinline__ f32x2 pkfma(f32x2 a, f32x2 b, f32x2 c){
    return __builtin_elementwise_fma(a, b, c);
}

__device__ __forceinline__ void gl2lds16(const void* g, void* l){
    __builtin_amdgcn_global_load_lds((const __attribute__((address_space(1))) void*)g,
                                     (__attribute__((address_space(3))) void*)l, 16, 0, 0);
}

// ---------------- fused fp32 -> bf16 casts (one launch) ----------------
struct Cast8 { const float* p[8]; };  // x, Wq, Wk, Wv, Wa, Wg, Wo, Wb
__global__ void cast_all_kernel(Cast8 args, unsigned short* __restrict__ xb,
                                unsigned short* __restrict__ Wcat,
                                unsigned short* __restrict__ Wob){
    int blk = blockIdx.x;
    if (blk >= 28704) {  // zero-pad rows 10256..10367 of Wcat
        int i = (blk - 28704)*1024 + threadIdx.x*4;
        *(ushort4*)(Wcat + (size_t)10256*2048 + i) = (ushort4){0,0,0,0};
        return;
    }
    const float* src; unsigned short* dst; int i;
    if (blk >= 28672) {  // Wb -> Wcat rows 10240..10255
        i = (blk - 28672)*1024 + threadIdx.x*4;
        src = args.p[7]; dst = Wcat + (size_t)10240*2048;
    } else {
        int seg = blk >> 12;
        i = (blk & 4095)*1024 + threadIdx.x*4;
        src = args.p[seg];
        if (seg == 0)      dst = xb;
        else if (seg <= 5) dst = Wcat + (size_t)(seg-1)*4194304;
        else               dst = Wob;
    }
    float4 f = *(const float4*)(src + i);
    ushort4 u; u.x = f2bf(f.x); u.y = f2bf(f.y); u.z = f2bf(f.z); u.w = f2bf(f.w);
    *(ushort4*)(dst + i) = u;
}

// ---------------- bf16 GEMM (m97-style): C[M,N] = A[M,K]*Bm[N,K]^T ----------------
// When aw != nullptr (gemm1): a-cols [6144,8192) are routed (sigmoided) to
// aw packed [bh][t][dim]; beta cols [10240,10256) to bw packed [bh][t];
// pad cols >=10256 are skipped. q/k/v/g go to C (Y) as before.
__global__ __launch_bounds__(256) void gemm_bt(
    const unsigned short* __restrict__ A,
    const unsigned short* __restrict__ Bm,
    float* __restrict__ C, int M, int N, int K,
    int act_start, const float* __restrict__ ba, const float* __restrict__ bbeta,
    float* __restrict__ aw, float* __restrict__ bw)
{
    __shared__ __align__(16) unsigned short lA[128*32];
    __shared__ __align__(16) unsigned short lB[128*32];
    const int tid  = threadIdx.x;
    const int wave = tid >> 6, lane = tid & 63;
    const int quad = lane >> 4, l16 = lane & 15;
    const int wm = wave >> 1, wn = wave & 1;
    const int m0 = blockIdx.y * 128, n0 = blockIdx.x * 128;

    const unsigned short* gsrcA[2];
    const unsigned short* gsrcB[2];
    unsigned short* ldst[2];
    #pragma unroll
    for (int i = 0; i < 2; i++) {
        int chunk = wave*128 + i*64 + lane;
        int r = chunk >> 2, p = chunk & 3;
        int gcb = p ^ (r & 3);
        gsrcA[i] = A  + (size_t)(m0 + r)*K + gcb*8;
        gsrcB[i] = Bm + (size_t)(n0 + r)*K + gcb*8;
        ldst[i]  = (unsigned short*)((char*)lA + (size_t)(wave*128 + i*64)*16);
    }
    const size_t lBoff = (size_t)((char*)lB - (char*)lA);

    f32x4 acc[4][4];
    #pragma unroll
    for (int i = 0; i < 4; i++)
        #pragma unroll
        for (int j = 0; j < 4; j++) acc[i][j] = (f32x4){0.f,0.f,0.f,0.f};

    for (int k0 = 0; k0 < K; k0 += 32) {
        __syncthreads();
        #pragma unroll
        for (int i = 0; i < 2; i++) {
            gl2lds16(gsrcA[i] + k0, ldst[i]);
            gl2lds16(gsrcB[i] + k0, (char*)ldst[i] + lBoff);
        }
        __syncthreads();
        bf16x8 af[4], bfr[4];
        #pragma unroll
        for (int i = 0; i < 4; i++) {
            int ra = wm*64 + i*16 + l16;
            int rb = wn*64 + i*16 + l16;
            af[i]  = *(const bf16x8*)(&lA[ra*32 + ((quad ^ (ra & 3))*8)]);
            bfr[i] = *(const bf16x8*)(&lB[rb*32 + ((quad ^ (rb & 3))*8)]);
        }
        #pragma unroll
        for (int i = 0; i < 4; i++)
            #pragma unroll
            for (int j = 0; j < 4; j++)
                acc[i][j] = __builtin_amdgcn_mfma_f32_16x16x32_bf16(af[i], bfr[j], acc[i][j], 0, 0, 0);
    }

    #pragma unroll
    for (int i = 0; i < 4; i++) {
        int m = m0 + wm*64 + i*16 + quad*4;
        #pragma unroll
        for (int j = 0; j < 4; j++) {
            int n = n0 + wn*64 + j*16 + l16;
            #pragma unroll
            for (int r = 0; r < 4; r++) {
                float y = acc[i][j][r];
                if (n >= act_start) {
                    float bsum = 0.0f;
                    if (n < 8192) bsum = ba[n - 6144];
                    else if (n >= 10240 && n < 10256) bsum = bbeta[n - 10240];
                    y = sigm(y + bsum);
                }
                if (aw) {
                    int m_ = m + r;
                    int b = m_ >> 10, t = m_ & 1023;
                    if (n < 6144 || (n >= 8192 && n < 10240)) {
                        C[(size_t)m_*N + n] = y;
                    } else if (n < 8192) {
                        aw[(size_t)((b<<4) + ((n - 6144) >> 7))*131072 + t*128 + (n & 127)] = y;
                    } else if (n >= 10240 && n < 10256) {
                        bw[(size_t)((b<<4) + (n - 10240))*1024 + t] = y;
                    } // pad cols >= 10256: skip
                } else {
                    C[(size_t)(m + r)*N + n] = y;
                }
            }
        }
    }
}

// ---------------- FUSED causal depthwise conv (K=4) + silu + scale for q,k,v ----------------
// 768 blocks (3 blocks/CU); which = conv id (block-uniform); t-chunks of 64;
// writes PACKED [bh][t][dim]. (PROVEN round 7.)
struct ConvAll { const float* w[3]; const float* bia[3]; float scale[3]; };
__global__ __launch_bounds__(256) void conv_silu_kernel(const float* __restrict__ Y, ConvAll ca,
                                 float* __restrict__ qs, float* __restrict__ ks,
                                 float* __restrict__ vs)
{
    int gid = blockIdx.x * 256 + threadIdx.x;   // 0..196607
    int which = gid >> 16;                      // 0..2 (block-uniform: 256 blocks per conv)
    int sub = gid & 65535;
    int c = sub & 2047;
    int tmp = sub >> 11;                        // 0..31
    int tch = tmp & 15;                         // 16 chunks of 64
    int b = tmp >> 4;
    int t0 = tch * 64;
    const float* cw = ca.w[which];
    const float w0 = cw[c*4+0], w1 = cw[c*4+1], w2 = cw[c*4+2], w3 = cw[c*4+3];
    const float bias = ca.bia[which][c];
    const float scale = ca.scale[which];
    const float* src = Y + (size_t)b*T_*YSTRIDE + which*2048 + c;
    float* outbase = (which == 0) ? qs : (which == 1) ? ks : vs;
    float* dst = outbase + (size_t)(b*16 + (c >> 7))*131072 + (c & 127);
    float y0 = (t0 >= 3) ? src[(size_t)(t0-3)*YSTRIDE] : 0.f;
    float y1 = (t0 >= 2) ? src[(size_t)(t0-2)*YSTRIDE] : 0.f;
    float y2 = (t0 >= 1) ? src[(size_t)(t0-1)*YSTRIDE] : 0.f;
    for (int t = t0; t < t0 + 64; t++) {
        float y3 = src[(size_t)t*YSTRIDE];
        float s = fmaf(w0,y0, fmaf(w1,y1, fmaf(w2,y2, fmaf(w3,y3, bias))));
        float r = s * (1.0f/(1.0f + __expf(-s))) * scale;
        dst[(size_t)t*128] = r;
        y0 = y1; y1 = y2; y2 = y3;
    }
}

// ---------------- G1 precompute: G1[bh][t] = <k(t), k(t+1)>, G1[.,1023]=0 ----------------
__global__ __launch_bounds__(256) void g1_kernel(const float* __restrict__ k,
                                                 float* __restrict__ g1)
{
    int wave = threadIdx.x >> 6, lane = threadIdx.x & 63;
    int half_id = blockIdx.x*8 + wave*2 + (lane >> 5);   // 0..32767
    int bh = half_id >> 10, t = half_id & 1023;
    const float4* kp = (const float4*)(k + (size_t)bh*131072 + (size_t)t*128) + (lane & 31);
    float4 x = kp[0];
    float4 y = {0.f,0.f,0.f,0.f};
    if (t < 1023) y = kp[32];
    f32x2 d = pkfma((f32x2){x.z,x.w}, (f32x2){y.z,y.w}, (f32x2){x.x,x.y} * (f32x2){y.x,y.y});
    float s = half_sum5(d.x + d.y);
    if ((lane & 31) == 31) g1[(size_t)bh*1024 + t] = s;
}

// ---------------- gated delta recurrence: lag-1 linearized scan (PROVEN round 6, 218us) ----------
// Lanes 0-31 own row rowA, lanes 32-63 own row rowA+64; 4 k-dims/lane (float4);
// half_sum5 + ds_swizzle(0x03E0) broadcast.  sk(t+1) = a(t)*rprev - c(t)*G1(t),
// rprev = <S(t-1),k(t+1)> issued one step early; o(t)=<S(t),q(t)> off-chain.
__global__ __launch_bounds__(256) void recurrence_kernel(
    const float* __restrict__ q, const float* __restrict__ k, const float* __restrict__ v,
    const float* __restrict__ a, const float* __restrict__ beta,
    const float* __restrict__ g1, float* __restrict__ o)
{
    const int blk = blockIdx.x;
    const int bh = blk & 31;              // == b*16 + h
    const int rowgrp = blk >> 5;          // 0..15
    const int lane = threadIdx.x & 63;
    const int wave = threadIdx.x >> 6;
    const int rowA = rowgrp*4 + wave;     // 0..63
    const int vrow = (lane < 32) ? rowA : rowA + 64;
    const size_t cb = (size_t)bh * 131072;
    const float4* kp = (const float4*)(k + cb) + (lane & 31);  // step stride 32 float4
    const float4* qp = (const float4*)(q + cb) + (lane & 31);
    const float*  vp = v + cb + vrow;
    const float*  ap = a + cb + vrow;
    const float*  bp = beta + (size_t)bh * 1024;
    const float*  gp = g1 + (size_t)bh * 1024;
    float*        op = o + cb + vrow;

    f32x2 s01 = {0.f, 0.f}, s23 = {0.f, 0.f};
    float sk = 0.f, rprev = 0.f;          // sk(t) and <S(t-1),k(t+1)>; valid lanes 31/63

    float4 kA[4], kB[4], kX[2];           // k groups g, g+1, head of g+2
    float4 qc[4], qn[4];
    float  vc[4], ac[4], bc[4], gc[4], vn[4], an[4], bn[4], gn[4];

    #pragma unroll
    for (int j = 0; j < 4; j++) {
        kA[j] = kp[j*32]; kB[j] = kp[(4+j)*32];
        qc[j] = qp[j*32]; qn[j] = qp[(4+j)*32];
        vc[j] = vp[j*128]; ac[j] = ap[j*128]; bc[j] = bp[j]; gc[j] = gp[j];
        vn[j] = vp[(4+j)*128]; an[j] = ap[(4+j)*128]; bn[j] = bp[4+j]; gn[j] = gp[4+j];
    }
    kX[0] = kp[8*32]; kX[1] = kp[9*32];

// kv = k(t); kv2 = k(t+2); chain: c_ -> sk fixup (2 fma). All else off-chain.
#define RSTEP(kv, kv2, qv, vt, at, bt, gt, oidx) { \
    float c_ = (bt) * (sk - (vt)); \
    sk = fmaf((at), rprev, -(c_ * (gt))); \
    float cl = __builtin_bit_cast(float, __builtin_amdgcn_ds_swizzle(__builtin_bit_cast(int, c_), 0x03E0)); \
    f32x2 k01 = {(kv).x, (kv).y}, k23 = {(kv).z, (kv).w}; \
    f32x2 c2 = {cl, cl}; \
    f32x2 a2 = {(at), (at)}; \
    s01 = pkfma(a2, s01, -(c2*k01)); \
    s23 = pkfma(a2, s23, -(c2*k23)); \
    f32x2 q01 = {(qv).x, (qv).y}, q23 = {(qv).z, (qv).w}; \
    f32x2 o2 = pkfma(s23, q23, s01*q01); \
    float ov_ = half_sum5(o2.x + o2.y); \
    if ((lane & 31) == 31) op[(size_t)(oidx)*128] = ov_; \
    f32x2 x01 = {(kv2).x, (kv2).y}, x23 = {(kv2).z, (kv2).w}; \
    f32x2 r2 = pkfma(s23, x23, s01*x01); \
    rprev = half_sum5(r2.x + r2.y); \
}

    #pragma unroll 1
    for (int t0 = 0; t0 < T_; t0 += 8) {
        // compute group c: t = t0..t0+3 (k(t+2): kA[2],kA[3],kB[0],kB[1])
        RSTEP(kA[0], kA[2], qc[0], vc[0], ac[0], bc[0], gc[0], t0+0)
        RSTEP(kA[1], kA[3], qc[1], vc[1], ac[1], bc[1], gc[1], t0+1)
        RSTEP(kA[2], kB[0], qc[2], vc[2], ac[2], bc[2], gc[2], t0+2)
        RSTEP(kA[3], kB[1], qc[3], vc[3], ac[3], bc[3], gc[3], t0+3)
        // reload A <- t0+8..11; c-streams <- t0+8..11 (last body overruns into
        // adjacent ws arrays; values in-bounds of ws, never consumed)
        #pragma unroll
        for (int j = 0; j < 4; j++) {
            int t = t0 + 8 + j;
            kA[j] = kp[t*32]; qc[j] = qp[t*32];
            vc[j] = vp[(size_t)t*128]; ac[j] = ap[(size_t)t*128]; bc[j] = bp[t]; gc[j] = gp[t];
        }
        // compute group n: t = t0+4..t0+7 (k(t+2): kB[2],kB[3],kX[0],kX[1])
        RSTEP(kB[0], kB[2], qn[0], vn[0], an[0], bn[0], gn[0], t0+4)
        RSTEP(kB[1], kB[3], qn[1], vn[1], an[1], bn[1], gn[1], t0+5)
        RSTEP(kB[2], kX[0], qn[2], vn[2], an[2], bn[2], gn[2], t0+6)
        RSTEP(kB[3], kX[1], qn[3], vn[3], an[3], bn[3], gn[3], t0+7)
        // reload B <- t0+12..15, X <- k(t0+16..17); n-streams <- t0+12..15
        #pragma unroll
        for (int j = 0; j < 4; j++) {
            int t = t0 + 12 + j;
            kB[j] = kp[t*32]; qn[j] = qp[t*32];
            vn[j] = vp[(size_t)t*128]; an[j] = ap[(size_t)t*128]; bn[j] = bp[t]; gn[j] = gp[t];
        }
        kX[0] = kp[(t0+16)*32]; kX[1] = kp[(t0+17)*32];
    }
#undef RSTEP
}

// ---------------- LayerNorm over DV, * gate, -> bf16 (reads packed ov) ----------------
__global__ __launch_bounds__(256) void ln_gate_kernel(
    const float* __restrict__ o, const float* __restrict__ g, int g_stride,
    const float* __restrict__ ln_g, const float* __restrict__ ln_b,
    unsigned short* __restrict__ og)
{
    int wave = threadIdx.x >> 6, lane = threadIdx.x & 63;
    int gidx = blockIdx.x*4 + wave;     // 0..32767
    int row = gidx >> 4, h = gidx & 15;
    int b = row >> 10, t = row & 1023;
    const float* ob = o + (size_t)(b*16 + h)*131072 + (size_t)t*128;
    int d0 = lane*2;
    float2 xv = *(const float2*)(ob + d0);
    float s = xv.x + xv.y, ss = xv.x*xv.x + xv.y*xv.y;
    for (int m = 1; m < 64; m <<= 1) { s += __shfl_xor(s, m); ss += __shfl_xor(ss, m); }
    float mu  = s * (1.f/128.f);
    float var = ss * (1.f/128.f) - mu*mu;
    float inv = rsqrtf(var + 1e-5f);
    const float* gb = g + (size_t)row*g_stride + h*128;
    float r0 = ((xv.x - mu)*inv*ln_g[d0]   + ln_b[d0])   * gb[d0];
    float r1 = ((xv.y - mu)*inv*ln_g[d0+1] + ln_b[d0+1]) * gb[d0+1];
    ushort2 u; u.x = f2bf(r0); u.y = f2bf(r1);
    *(ushort2*)(og + (size_t)row*2048 + h*128 + d0) = u;
}

extern "C" void kernel_launch(void* const* d_in, const int* in_sizes, int n_in,
                              void* d_out, int out_size, void* d_ws, size_t ws_size,
                              hipStream_t stream)
{
    const float* x   = (const float*)d_in[0];
    const float* Wq  = (const float*)d_in[1];
    const float* Wk  = (const float*)d_in[2];
    const float* Wv  = (const float*)d_in[3];
    const float* Wa  = (const float*)d_in[4];
    const float* ba  = (const float*)d_in[5];
    const float* Wb  = (const float*)d_in[6];
    const float* bb  = (const float*)d_in[7];
    const float* cqw = (const float*)d_in[8];
    const float* cqb = (const float*)d_in[9];
    const float* ckw = (const float*)d_in[10];
    const float* ckb = (const float*)d_in[11];
    const float* cvw = (const float*)d_in[12];
    const float* cvb = (const float*)d_in[13];
    const float* Wg  = (const float*)d_in[14];
    const float* lng = (const float*)d_in[15];
    const float* lnb = (const float*)d_in[16];
    const float* Wo  = (const float*)d_in[17];
    float* out = (float*)d_out;

    char* ws = (char*)d_ws;
    size_t off = 0;
    auto alloc = [&](size_t bytes){ void* p = ws + off; off += (bytes + 255) & ~(size_t)255; return p; };
    unsigned short* xb   = (unsigned short*)alloc((size_t)ROWS*D_*2);   // reused as og
    unsigned short* Wcat = (unsigned short*)alloc((size_t)NCAT*D_*2);   // reused as apack/bpack/g1 after gemm1
    unsigned short* Wob  = (unsigned short*)alloc((size_t)D_*D_*2);
    float* Y  = (float*)alloc((size_t)ROWS*YSTRIDE*4);
    float* qs = (float*)alloc((size_t)ROWS*2048*4);   // packed [bh][t][128]
    float* ks = (float*)alloc((size_t)ROWS*2048*4);   // packed
    float* vs = (float*)alloc((size_t)ROWS*2048*4);   // packed
    float* ov = (float*)alloc((size_t)ROWS*2048*4);   // packed
    unsigned short* og = xb;
    float* apack = (float*)Wcat;                       // 16MB, alias (Wcat bf16 data dead... see note)
    float* bpack = apack + (size_t)32*1024*128;        // 128KB
    float* g1    = bpack + (size_t)32*1024;            // 128KB, still within Wcat (40.5MB)
    (void)ws_size;
    // NOTE: gemm1 writes apack/bpack (aliasing Wcat's tail region rows) WHILE
    // reading Wcat rows as the B operand.  apack starts at Wcat row 0 in float
    // units -- gemm1 reads Wcat rows up to 10368 (bf16, 40.5MB) and apack spans
    // 16.4MB from the base.  Row n of Wcat (bf16) occupies bytes [n*4096,
    // (n+1)*4096); apack bytes [0, 16.4MB) overlap Wcat rows 0..4194 -- which
    // ARE still being read by gemm1 blocks computing q/k columns!  To avoid the
    // alias hazard, place apack/bpack AFTER the live Wcat data instead:
    // (handled below by reassigning pointers past Wcat's 40.5MB.)
    // Wcat occupies 10368*2048*2 = 42467328 B.  Its alloc rounds to 42467328.
    // We carve apack from Y's tail instead: Y is 2048*10368*4 = 84.9MB, of
    // which columns 0..10240 are live.  Use the ws region AFTER ov by
    // allocating fresh space (ws is large):
    float* apack2 = (float*)alloc((size_t)ROWS*2048*4);   // 16.8MB packed a
    float* bpack2 = (float*)alloc((size_t)32*1024*4);     // 128KB packed beta
    float* g1b    = (float*)alloc((size_t)32*1024*4);     // 128KB g1
    apack = apack2; bpack = bpack2; g1 = g1b;

    Cast8 cargs;
    cargs.p[0]=x; cargs.p[1]=Wq; cargs.p[2]=Wk; cargs.p[3]=Wv; cargs.p[4]=Wa;
    cargs.p[5]=Wg; cargs.p[6]=Wo; cargs.p[7]=Wb;
    cast_all_kernel<<<28928, 256, 0, stream>>>(cargs, xb, Wcat, Wob);

    // fused projections + beta: [2048,10368] = xb @ Wcat^T
    // a-cols -> apack (packed, sigmoided), beta-cols -> bpack; pad skipped.
    gemm_bt<<<dim3(81,16), 256, 0, stream>>>(xb, Wcat, Y, ROWS, NCAT, D_, 6144, ba, bb, apack, bpack);

    // fused q/k/v causal conv + silu (+ k scale), one launch, 3 blocks/CU
    const float kscale = 0.08838834764831845f;  // DK^-0.5
    ConvAll ca;
    ca.w[0]=cqw; ca.w[1]=ckw; ca.w[2]=cvw;
    ca.bia[0]=cqb; ca.bia[1]=ckb; ca.bia[2]=cvb;
    ca.scale[0]=1.0f; ca.scale[1]=kscale; ca.scale[2]=1.0f;
    conv_silu_kernel<<<768, 256, 0, stream>>>(Y, ca, qs, ks, vs);

    // G1(t) = <k(t),k(t+1)> per (bh,t)
    g1_kernel<<<4096, 256, 0, stream>>>(ks, g1);

    // 512 blocks x 4 waves; each wave: 2 v-rows (lane halves)
    recurrence_kernel<<<512, 256, 0, stream>>>(qs, ks, vs, apack, bpack, g1, ov);

    ln_gate_kernel<<<8192, 256, 0, stream>>>(ov, Y + 8192, YSTRIDE, lng, lnb, og);

    gemm_bt<<<dim3(16,16), 256, 0, stream>>>(og, Wob, out, ROWS, D_, D_, 1<<30, nullptr, nullptr, nullptr, nullptr);
}